// Round 8
// baseline (1150.379 us; speedup 1.0000x reference)
//
#include <hip/hip_runtime.h>
#include <stdint.h>

typedef unsigned short u16;
typedef __attribute__((ext_vector_type(8))) __bf16 bf16x8;
typedef __attribute__((ext_vector_type(4))) float f32x4;

__device__ __forceinline__ float bf2f(u16 u) {
    return __uint_as_float(((unsigned int)u) << 16);
}
__device__ __forceinline__ u16 f2bf(float f) {
    unsigned int u = __float_as_uint(f);
    u += 0x7fffu + ((u >> 16) & 1u);   // round-to-nearest-even
    return (u16)(u >> 16);
}

// async global->LDS, 16B per lane.  LDS dest = wave-uniform base + lane*16.
__device__ __forceinline__ void gl16(const u16* g, u16* l) {
    __builtin_amdgcn_global_load_lds(
        (const __attribute__((address_space(1))) unsigned int*)(uintptr_t)g,
        (__attribute__((address_space(3))) unsigned int*)(uintptr_t)l,
        16, 0, 0);
}

// ---------------------------------------------------------------------------
// Merged f32 -> bf16 weight conversion: all 6 weight tensors in one launch.
// Block ranges (each block = 256 float4): wqkv_t 3072 | wo_t 1024 |
// wqkv_s 3072 | wo_s 1024 | fc 4096 | proj 4096   (total 16384 blocks)
// ---------------------------------------------------------------------------
__global__ __launch_bounds__(256) void cvt_all(const float4* __restrict__ a0, ushort4* __restrict__ o0,
                                               const float4* __restrict__ a1, ushort4* __restrict__ o1,
                                               const float4* __restrict__ a2, ushort4* __restrict__ o2,
                                               const float4* __restrict__ a3, ushort4* __restrict__ o3,
                                               const float4* __restrict__ a4, ushort4* __restrict__ o4,
                                               const float4* __restrict__ a5, ushort4* __restrict__ o5) {
    int b = blockIdx.x;
    const float4* src; ushort4* dst; int base;
    if      (b < 3072)  { src = a0; dst = o0; base = 0; }
    else if (b < 4096)  { src = a1; dst = o1; base = 3072; }
    else if (b < 7168)  { src = a2; dst = o2; base = 4096; }
    else if (b < 8192)  { src = a3; dst = o3; base = 7168; }
    else if (b < 12288) { src = a4; dst = o4; base = 8192; }
    else                { src = a5; dst = o5; base = 12288; }
    int tid = (b - base) * 256 + threadIdx.x;
    float4 v = src[tid];
    ushort4 o;
    o.x = f2bf(v.x); o.y = f2bf(v.y); o.z = f2bf(v.z); o.w = f2bf(v.w);
    dst[tid] = o;
}

// pos_w [1024][27] -> wt [27][1024] (float)
__global__ __launch_bounds__(256) void cvt_wt(const float* __restrict__ pw,
                                              float* __restrict__ wt) {
    int tid = blockIdx.x * 256 + threadIdx.x;   // 27648
    if (tid < 27648) {
        int tap = tid >> 10, c = tid & 1023;
        wt[tid] = pw[c * 27 + tap];
    }
}

// ---------------------------------------------------------------------------
// Depthwise 3x3x3 conv positional embedding, float4 vectorized.
// Loop nest restructured: spatial (di,dj) outer with hoisted base address;
// temporal tap inner costs one add (+tt*2048) + weight offset (+dt*2304).
// rf (and thus t,i,j and all branch predicates) is block-uniform.
// ---------------------------------------------------------------------------
__global__ __launch_bounds__(256) void posembed(const float4* __restrict__ x4,
                                                const float4* __restrict__ wt4,
                                                const float4* __restrict__ pb4,
                                                float4* __restrict__ out4) {
    int tid = blockIdx.x * 256 + threadIdx.x;   // 1569*2048 total
    float4 xv = x4[tid];
    int rf = tid >> 11;
    if (rf == 0) { out4[tid] = xv; return; }
    int c4 = tid & 255;
    int nc = tid & 2047;                        // (n<<8) + c4
    int r = rf - 1;
    int t = r & 7, l = r >> 3;
    int i = l / 14, j = l - i * 14;
    float4 pbv = pb4[c4];
    float a0 = xv.x + pbv.x, a1 = xv.y + pbv.y, a2 = xv.z + pbv.z, a3 = xv.w + pbv.w;
    const float4* wbase = wt4 + c4;
#pragma unroll
    for (int di = 0; di < 3; di++) {
        int ii = i + di - 1;
        if (ii < 0 || ii > 13) continue;
#pragma unroll
        for (int dj = 0; dj < 3; dj++) {
            int jj = j + dj - 1;
            if (jj < 0 || jj > 13) continue;
            size_t vbase = (size_t)(1 + ((ii * 14 + jj) << 3)) * 2048 + nc;
            int woff = (di * 3 + dj) * 256;
#pragma unroll
            for (int dt = 0; dt < 3; dt++) {
                int tt = t + dt - 1;
                if (tt < 0 || tt > 7) continue;
                float4 w4 = wbase[woff + dt * 2304];        // (dt*9+di*3+dj)*256
                float4 v = x4[vbase + (size_t)tt * 2048];
                a0 += w4.x * v.x; a1 += w4.y * v.y; a2 += w4.z * v.z; a3 += w4.w * v.w;
            }
        }
    }
    out4[tid] = (float4){a0, a1, a2, a3};
}

// ---------------------------------------------------------------------------
// LayerNorm with branch-specific row gather, f32 in -> bf16 out.
// ---------------------------------------------------------------------------
__global__ __launch_bounds__(256) void ln_kernel(const float* __restrict__ resid,
                                                 const u16* __restrict__ Radd,
                                                 const float* __restrict__ g,
                                                 const float* __restrict__ bb,
                                                 u16* __restrict__ out, int mode) {
    int ro = blockIdx.x;
    int tid = threadIdx.x;
    int src, n;
    long long rarow = -1;
    if (mode == 0) {
        int t = ro / 1568, b2 = ro - t * 1568;
        n = b2 / 196;
        int l = b2 - n * 196;
        src = 1 + l * 8 + t;
    } else if (mode == 1) {
        int s = ro >> 6, u = ro & 63;
        int t = u >> 3;
        n = u & 7;
        if (s == 0) src = 0;
        else { src = 1 + (s - 1) * 8 + t; rarow = (long long)(t * 1568 + n * 196 + (s - 1)); }
    } else {
        src = ro >> 3;
        n = ro & 7;
    }
    const float* xp = resid + ((size_t)src * 8 + n) * 1024 + tid * 4;
    float4 xv = *(const float4*)xp;
    float x0 = xv.x, x1 = xv.y, x2 = xv.z, x3 = xv.w;
    if (rarow >= 0) {
        const u16* rp = Radd + rarow * 1024 + tid * 4;
        x0 += bf2f(rp[0]); x1 += bf2f(rp[1]); x2 += bf2f(rp[2]); x3 += bf2f(rp[3]);
    }
    float s1 = x0 + x1 + x2 + x3;
    float s2 = x0 * x0 + x1 * x1 + x2 * x2 + x3 * x3;
#pragma unroll
    for (int off = 32; off > 0; off >>= 1) {
        s1 += __shfl_down(s1, off);
        s2 += __shfl_down(s2, off);
    }
    __shared__ float red[8];
    int lane = tid & 63, w = tid >> 6;
    if (lane == 0) { red[w] = s1; red[4 + w] = s2; }
    __syncthreads();
    float S1 = red[0] + red[1] + red[2] + red[3];
    float S2 = red[4] + red[5] + red[6] + red[7];
    float mean = S1 * (1.f / 1024.f);
    float var = S2 * (1.f / 1024.f) - mean * mean;
    float rstd = rsqrtf(var + 1e-5f);
    int c = tid * 4;
    float4 gv = *(const float4*)(g + c);
    float4 bv = *(const float4*)(bb + c);
    u16* op = out + (size_t)ro * 1024 + c;
    op[0] = f2bf((x0 - mean) * rstd * gv.x + bv.x);
    op[1] = f2bf((x1 - mean) * rstd * gv.y + bv.y);
    op[2] = f2bf((x2 - mean) * rstd * gv.z + bv.z);
    op[3] = f2bf((x3 - mean) * rstd * gv.w + bv.w);
}

// ---------------------------------------------------------------------------
// Proven 128x128 GEMM (BK=32, 2-barrier, ~2.4 blocks/CU co-resident).
// Used for the K=1024 GEMMs (QKV x2, wo_t, FC).
// ---------------------------------------------------------------------------
__global__ __launch_bounds__(256) void gemm_bf16(const u16* __restrict__ A,
                                                 const u16* __restrict__ W,
                                                 const float* __restrict__ bias,
                                                 u16* __restrict__ Co,
                                                 int M, int N, int K, int gelu,
                                                 int nx) {
    __shared__ u16 As[2][128 * 32];
    __shared__ u16 Bs[2][128 * 32];
    int tid = threadIdx.x;
    int T = gridDim.x;                       // divisible by 8
    int bid = blockIdx.x;
    int w_ = (bid & 7) * (T >> 3) + (bid >> 3);   // XCD g gets contiguous work range
    int n0 = (w_ % nx) * 128;
    int m0 = (w_ / nx) * 128;
    int lane = tid & 63, wid = tid >> 6;
    int wm = (wid >> 1) * 64, wn = (wid & 1) * 64;
    int lm = lane & 15, q = lane >> 4;

    f32x4 acc[4][4];
#pragma unroll
    for (int i = 0; i < 4; i++)
#pragma unroll
        for (int j = 0; j < 4; j++) acc[i][j] = (f32x4){0.f, 0.f, 0.f, 0.f};

    // staging map: wave w chunk c (c=0,1): lane l -> row w*32+c*16+(l>>2), col bf16 (l&3)*8
    int r0 = wid * 32 + (lane >> 2);
    int colb = (lane & 3) * 8;
    int mA0 = m0 + r0;          if (mA0 > M - 1) mA0 = M - 1;
    int mA1 = m0 + r0 + 16;     if (mA1 > M - 1) mA1 = M - 1;
    const u16* gA0 = A + (size_t)mA0 * K + colb;
    const u16* gA1 = A + (size_t)mA1 * K + colb;
    const u16* gB0 = W + (size_t)(n0 + r0) * K + colb;
    const u16* gB1 = W + (size_t)(n0 + r0 + 16) * K + colb;
    int wo = wid * 1024;

    auto loadt = [&](int b) {
        gl16(gA0, &As[b][wo]); gl16(gA1, &As[b][wo + 512]);
        gl16(gB0, &Bs[b][wo]); gl16(gB1, &Bs[b][wo + 512]);
        gA0 += 32; gA1 += 32; gB0 += 32; gB1 += 32;
    };
    auto comput = [&](int b) {
        bf16x8 af[4], bfr[4];
#pragma unroll
        for (int i = 0; i < 4; i++) af[i] = *(const bf16x8*)&As[b][(wm + i * 16 + lm) * 32 + q * 8];
#pragma unroll
        for (int j = 0; j < 4; j++) bfr[j] = *(const bf16x8*)&Bs[b][(wn + j * 16 + lm) * 32 + q * 8];
#pragma unroll
        for (int i = 0; i < 4; i++)
#pragma unroll
            for (int j = 0; j < 4; j++)
                acc[i][j] = __builtin_amdgcn_mfma_f32_16x16x32_bf16(af[i], bfr[j], acc[i][j], 0, 0, 0);
    };

    int Tt = K >> 5;                       // tiles; K is a multiple of 64
    loadt(0);
    __syncthreads();
    loadt(1); comput(0); __syncthreads();
    for (int t = 2; t + 1 < Tt; t += 2) {
        loadt(0); comput(1); __syncthreads();
        loadt(1); comput(0); __syncthreads();
    }
    comput(1);

#pragma unroll
    for (int i = 0; i < 4; i++) {
        int row_b = m0 + wm + i * 16 + q * 4;
#pragma unroll
        for (int j = 0; j < 4; j++) {
            int col = n0 + wn + j * 16 + lm;
            float bv = bias[col];
#pragma unroll
            for (int r = 0; r < 4; r++) {
                int row = row_b + r;
                if (row < M) {
                    float v = acc[i][j][r] + bv;
                    if (gelu) v = v / (1.f + __expf(-1.702f * v));  // QuickGELU
                    Co[(size_t)row * N + col] = f2bf(v);
                }
            }
        }
    }
}

// ---------------------------------------------------------------------------
// wo_s GEMM (M=12608, N=1024, K=1024) with FUSED spatial residual scatter-add:
//   rows <  64 (cls, s=0): bf16 -> Rbuf (consumed by add_cls reduction)
//   rows >= 64: resid[(1+(s-1)*8+t)*8+n][col] += acc+bias   (f32 RMW)
// ---------------------------------------------------------------------------
__global__ __launch_bounds__(256) void gemm_wos(const u16* __restrict__ A,
                                                const u16* __restrict__ W,
                                                const float* __restrict__ bias,
                                                u16* __restrict__ Rb,
                                                float* __restrict__ resid,
                                                int M, int nx) {
    const int N = 1024, K = 1024;
    __shared__ u16 As[2][128 * 32];
    __shared__ u16 Bs[2][128 * 32];
    int tid = threadIdx.x;
    int T = gridDim.x;
    int bid = blockIdx.x;
    int w_ = (bid & 7) * (T >> 3) + (bid >> 3);
    int n0 = (w_ % nx) * 128;
    int m0 = (w_ / nx) * 128;
    int lane = tid & 63, wid = tid >> 6;
    int wm = (wid >> 1) * 64, wn = (wid & 1) * 64;
    int lm = lane & 15, q = lane >> 4;

    f32x4 acc[4][4];
#pragma unroll
    for (int i = 0; i < 4; i++)
#pragma unroll
        for (int j = 0; j < 4; j++) acc[i][j] = (f32x4){0.f, 0.f, 0.f, 0.f};

    int r0 = wid * 32 + (lane >> 2);
    int colb = (lane & 3) * 8;
    int mA0 = m0 + r0;          if (mA0 > M - 1) mA0 = M - 1;
    int mA1 = m0 + r0 + 16;     if (mA1 > M - 1) mA1 = M - 1;
    const u16* gA0 = A + (size_t)mA0 * K + colb;
    const u16* gA1 = A + (size_t)mA1 * K + colb;
    const u16* gB0 = W + (size_t)(n0 + r0) * K + colb;
    const u16* gB1 = W + (size_t)(n0 + r0 + 16) * K + colb;
    int wo = wid * 1024;

    auto loadt = [&](int b) {
        gl16(gA0, &As[b][wo]); gl16(gA1, &As[b][wo + 512]);
        gl16(gB0, &Bs[b][wo]); gl16(gB1, &Bs[b][wo + 512]);
        gA0 += 32; gA1 += 32; gB0 += 32; gB1 += 32;
    };
    auto comput = [&](int b) {
        bf16x8 af[4], bfr[4];
#pragma unroll
        for (int i = 0; i < 4; i++) af[i] = *(const bf16x8*)&As[b][(wm + i * 16 + lm) * 32 + q * 8];
#pragma unroll
        for (int j = 0; j < 4; j++) bfr[j] = *(const bf16x8*)&Bs[b][(wn + j * 16 + lm) * 32 + q * 8];
#pragma unroll
        for (int i = 0; i < 4; i++)
#pragma unroll
            for (int j = 0; j < 4; j++)
                acc[i][j] = __builtin_amdgcn_mfma_f32_16x16x32_bf16(af[i], bfr[j], acc[i][j], 0, 0, 0);
    };

    int Tt = K >> 5;
    loadt(0);
    __syncthreads();
    loadt(1); comput(0); __syncthreads();
    for (int t = 2; t + 1 < Tt; t += 2) {
        loadt(0); comput(1); __syncthreads();
        loadt(1); comput(0); __syncthreads();
    }
    comput(1);

#pragma unroll
    for (int i = 0; i < 4; i++) {
        int row_b = m0 + wm + i * 16 + q * 4;
#pragma unroll
        for (int j = 0; j < 4; j++) {
            int col = n0 + wn + j * 16 + lm;
            float bv = bias[col];
#pragma unroll
            for (int r = 0; r < 4; r++) {
                int row = row_b + r;
                if (row < M) {
                    float v = acc[i][j][r] + bv;
                    if (row < 64) {
                        Rb[(size_t)row * N + col] = f2bf(v);
                    } else {
                        int s = row >> 6, u = row & 63;
                        int t2 = u >> 3, n = u & 7;
                        size_t o = ((size_t)(1 + (s - 1) * 8 + t2) * 8 + n) * 1024 + col;
                        resid[o] = resid[o] + v;
                    }
                }
            }
        }
    }
}

// ---------------------------------------------------------------------------
// bf16 MFMA GEMM, 256x256 tile, BK=64, 8-wave, 8-phase schedule.
// Used for the proj GEMM (K=4096 long-K regime) with fused f32 residual out:
//   Fout[row,col] += acc + bias
// ---------------------------------------------------------------------------
__global__ __launch_bounds__(512) void gemm256(const u16* __restrict__ A,
                                               const u16* __restrict__ W,
                                               const float* __restrict__ bias,
                                               u16* __restrict__ Co,
                                               float* __restrict__ Fout,
                                               int M, int N, int K, int gelu,
                                               int nnt) {
    __shared__ __align__(16) u16 sA[2][16384];   // [buf][256 rows x 64 cols]
    __shared__ __align__(16) u16 sB[2][16384];
    int tid = threadIdx.x;
    int wid = tid >> 6, lane = tid & 63;
    int wr = wid >> 2, wc = wid & 3;
    int lm = lane & 15, q = lane >> 4;

    // bijective XCD swizzle (m204)
    int nwg = gridDim.x, orig = blockIdx.x;
    int qq = nwg >> 3, rr = nwg & 7, xcd = orig & 7, blk = orig >> 3;
    int wg = (xcd < rr ? xcd * (qq + 1) : rr * (qq + 1) + (xcd - rr) * qq) + blk;
    int n0 = (wg % nnt) * 256, m0 = (wg / nnt) * 256;

    int NT = K >> 6, NTm1 = NT - 1;

    // staging: thread covers LDS row rl (+64/part, +128/half), chunk lane&7.
    // Global source pre-swizzled: phys chunk c of row r holds logical c^(r&7).
    int rl = wid * 8 + (lane >> 3);
    int cl = ((lane & 7) ^ (rl & 7)) * 8;
    const u16* pA[4];
    const u16* pB[4];
#pragma unroll
    for (int h2 = 0; h2 < 4; h2++) {
        int ra = m0 + h2 * 64 + rl; if (ra > M - 1) ra = M - 1;
        int rb = n0 + h2 * 64 + rl; if (rb > N - 1) rb = N - 1;
        pA[h2] = A + (size_t)ra * K + cl;
        pB[h2] = W + (size_t)rb * K + cl;
    }
    int ldst = wid * 512;

    f32x4 acc[8][4];
#pragma unroll
    for (int i = 0; i < 8; i++)
#pragma unroll
        for (int j = 0; j < 4; j++) acc[i][j] = (f32x4){0.f, 0.f, 0.f, 0.f};

    bf16x8 af[4][2];
    bf16x8 bfv[4][2];

#define STG(P, D, b, h, kt) do { \
        int _k = (kt); if (_k > NTm1) _k = NTm1; \
        gl16(P[(h) * 2] + (size_t)_k * 64, &D[b][(h) * 8192 + ldst]); \
        gl16(P[(h) * 2 + 1] + (size_t)_k * 64, &D[b][(h) * 8192 + 4096 + ldst]); \
    } while (0)
#define LDA_(b, ih) do { \
        _Pragma("unroll") for (int iq = 0; iq < 4; iq++) \
        _Pragma("unroll") for (int kk = 0; kk < 2; kk++) \
            af[iq][kk] = *(const bf16x8*)&sA[b][((ih) * 128 + wr * 64 + iq * 16 + lm) * 64 + \
                                                (((q + kk * 4) ^ (lm & 7)) * 8)]; \
    } while (0)
#define LDB_(b, jh) do { \
        _Pragma("unroll") for (int jq = 0; jq < 2; jq++) \
        _Pragma("unroll") for (int kk = 0; kk < 2; kk++) \
            bfv[(jh) * 2 + jq][kk] = *(const bf16x8*)&sB[b][((jh) * 128 + wc * 32 + jq * 16 + lm) * 64 + \
                                                            (((q + kk * 4) ^ (lm & 7)) * 8)]; \
    } while (0)
#define MMA_(ih, jh) do { \
        __builtin_amdgcn_s_setprio(1); \
        _Pragma("unroll") for (int iq = 0; iq < 4; iq++) \
        _Pragma("unroll") for (int jq = 0; jq < 2; jq++) \
        _Pragma("unroll") for (int kk = 0; kk < 2; kk++) \
            acc[(ih) * 4 + iq][(jh) * 2 + jq] = __builtin_amdgcn_mfma_f32_16x16x32_bf16( \
                af[iq][kk], bfv[(jh) * 2 + jq][kk], acc[(ih) * 4 + iq][(jh) * 2 + jq], 0, 0, 0); \
        __builtin_amdgcn_s_setprio(0); \
    } while (0)
#define BAR asm volatile("s_barrier" ::: "memory")
#define VM6 asm volatile("s_waitcnt vmcnt(6)" ::: "memory")

    // prologue: tile0 fully + tile1 {A0, B1, A1}; vmcnt(6) -> tile0 landed.
    STG(pA, sA, 0, 0, 0);
    STG(pA, sA, 0, 1, 0);
    STG(pB, sB, 0, 0, 0);
    STG(pB, sB, 0, 1, 0);
    STG(pA, sA, 1, 0, 1);
    STG(pB, sB, 1, 1, 1);
    STG(pA, sA, 1, 1, 1);
    VM6;
    BAR;

    int S = NT >> 1;
    for (int s = 0; s < S; s++) {
        int t = s * 2;
        LDA_(0, 0); LDB_(0, 0);
        STG(pB, sB, 1, 0, t + 1);
        BAR; MMA_(0, 0); BAR;
        LDB_(0, 1);
        STG(pA, sA, 0, 0, t + 2);
        BAR; MMA_(0, 1); BAR;
        LDA_(0, 1);
        STG(pB, sB, 0, 1, t + 2);
        BAR; MMA_(1, 1); BAR;
        STG(pA, sA, 0, 1, t + 2);
        VM6;
        BAR; MMA_(1, 0); BAR;
        LDA_(1, 0); LDB_(1, 0);
        STG(pB, sB, 0, 0, t + 2);
        BAR; MMA_(0, 0); BAR;
        LDB_(1, 1);
        STG(pA, sA, 1, 0, t + 3);
        BAR; MMA_(0, 1); BAR;
        LDA_(1, 1);
        STG(pB, sB, 1, 1, t + 3);
        BAR; MMA_(1, 1); BAR;
        STG(pA, sA, 1, 1, t + 3);
        VM6;
        BAR; MMA_(1, 0); BAR;
    }
    asm volatile("s_waitcnt vmcnt(0)" ::: "memory");   // drain tail prefetches

    // epilogue: bias + optional QuickGELU; bf16 store, or fused f32 resid +=
#pragma unroll
    for (int ih = 0; ih < 2; ih++)
#pragma unroll
        for (int iq = 0; iq < 4; iq++) {
            int row_b = m0 + ih * 128 + wr * 64 + iq * 16 + q * 4;
#pragma unroll
            for (int jh = 0; jh < 2; jh++)
#pragma unroll
                for (int jq = 0; jq < 2; jq++) {
                    int col = n0 + jh * 128 + wc * 32 + jq * 16 + lm;
                    float bv = bias[col];
#pragma unroll
                    for (int r = 0; r < 4; r++) {
                        int row = row_b + r;
                        if (row < M) {
                            float v = acc[ih * 4 + iq][jh * 2 + jq][r] + bv;
                            if (gelu) v = v / (1.f + __expf(-1.702f * v));  // QuickGELU
                            if (Fout) {
                                size_t o = (size_t)row * N + col;
                                Fout[o] = Fout[o] + v;
                            } else {
                                Co[(size_t)row * N + col] = f2bf(v);
                            }
                        }
                    }
                }
        }
#undef STG
#undef LDA_
#undef LDB_
#undef MMA_
#undef BAR
#undef VM6
}

// ---------------------------------------------------------------------------
// Temporal attention: S=8.  4 (b,h) pairs per 256-thread block (one wave
// each); 1568%4==0 so all four share h.  Vectorized ushort4 staging.
// ---------------------------------------------------------------------------
__global__ __launch_bounds__(256) void attn_t(const u16* __restrict__ qkv,
                                              const float* __restrict__ rpb,
                                              u16* __restrict__ out) {
    int w = threadIdx.x >> 6, d = threadIdx.x & 63;
    int bh = blockIdx.x * 4 + w;           // 6272 blocks cover 25088 pairs
    int b = bh % 1568, h = bh / 1568;
    __shared__ float qs[4][8][68], ks[4][8][68], vs[4][8][68];
    __shared__ float ps[4][8][9];
#pragma unroll
    for (int tt = 0; tt < 2; tt++) {
        int t = tt * 4 + (d >> 4);
        int c4 = (d & 15) * 4;
        size_t row = (size_t)(t * 1568 + b) * 3072 + h * 64 + c4;
        ushort4 qv = *(const ushort4*)(qkv + row);
        ushort4 kv = *(const ushort4*)(qkv + row + 1024);
        ushort4 vv = *(const ushort4*)(qkv + row + 2048);
        qs[w][t][c4 + 0] = bf2f(qv.x) * 0.125f; qs[w][t][c4 + 1] = bf2f(qv.y) * 0.125f;
        qs[w][t][c4 + 2] = bf2f(qv.z) * 0.125f; qs[w][t][c4 + 3] = bf2f(qv.w) * 0.125f;
        ks[w][t][c4 + 0] = bf2f(kv.x); ks[w][t][c4 + 1] = bf2f(kv.y);
        ks[w][t][c4 + 2] = bf2f(kv.z); ks[w][t][c4 + 3] = bf2f(kv.w);
        vs[w][t][c4 + 0] = bf2f(vv.x); vs[w][t][c4 + 1] = bf2f(vv.y);
        vs[w][t][c4 + 2] = bf2f(vv.z); vs[w][t][c4 + 3] = bf2f(vv.w);
    }
    __syncthreads();
    int tq = d >> 3, tk = d & 7;
    float s = rpb[(tq - tk + 7) * 16 + h];
#pragma unroll
    for (int dd = 0; dd < 64; dd++) s += qs[w][tq][dd] * ks[w][tk][dd];
    float mx = s;
    mx = fmaxf(mx, __shfl_xor(mx, 1));
    mx = fmaxf(mx, __shfl_xor(mx, 2));
    mx = fmaxf(mx, __shfl_xor(mx, 4));
    float p = __expf(s - mx);
    float su = p;
    su += __shfl_xor(su, 1);
    su += __shfl_xor(su, 2);
    su += __shfl_xor(su, 4);
    ps[w][tq][tk] = p / su;
    __syncthreads();
#pragma unroll
    for (int t2 = 0; t2 < 8; t2++) {
        float o = 0.f;
#pragma unroll
        for (int k2 = 0; k2 < 8; k2++) o += ps[w][t2][k2] * vs[w][k2][d];
        out[(size_t)(t2 * 1568 + b) * 1024 + h * 64 + d] = f2bf(o);
    }
}

// ---------------------------------------------------------------------------
// Spatial attention, MFMA version.  S'=197 (13 q-tiles of 16, 13 k-tiles),
// one block(256)=4 waves per (u=t*8+n, h).
// ---------------------------------------------------------------------------
#define KLS 72
#define PVS 232
__global__ __launch_bounds__(256) void attn_s(const u16* __restrict__ qkv,
                                              const float* __restrict__ rpb,
                                              u16* __restrict__ out) {
    __shared__ u16 Kl[208 * KLS];        // [key][feat], rows 197..207 zero
    __shared__ u16 Vt[64 * PVS];         // [feat][key], cols 197..231 zero
    __shared__ u16 Pl[4][16 * PVS];      // per-wave P tile [qlocal][key]
    __shared__ float rpb_l[736];
    int blk = blockIdx.x;
    int u = blk & 63, h = blk >> 6;
    int tid = threadIdx.x;
    int w = tid >> 6, lane = tid & 63;
    int lm = lane & 15, quad = lane >> 4;

    // ---- stage K, V^T ----
    for (int idx = tid; idx < 197 * 8; idx += 256) {
        int s = idx >> 3, c8 = idx & 7;
        const u16* gp = qkv + (size_t)(s * 64 + u) * 3072 + h * 64 + c8 * 8;
        uint4 kv = *(const uint4*)(gp + 1024);
        uint4 vv = *(const uint4*)(gp + 2048);
        *(uint4*)&Kl[s * KLS + c8 * 8] = kv;
        const u16* vp = (const u16*)&vv;
#pragma unroll
        for (int j = 0; j < 8; j++) Vt[(c8 * 8 + j) * PVS + s] = vp[j];
    }
    for (int i = tid; i < 11 * KLS; i += 256) Kl[197 * KLS + i] = 0;
    for (int i = tid; i < 64 * 35; i += 256) {
        int dd = i / 35, c = 197 + (i - dd * 35);
        Vt[dd * PVS + c] = 0;
    }
    { // zero P pad cols 208..223 (never rewritten)
        for (int i = lane; i < 256; i += 64) {
            int r = i >> 4, c = 208 + (i & 15);
            Pl[w][r * PVS + c] = 0;
        }
    }
    for (int i = tid; i < 729; i += 256) rpb_l[i] = rpb[i * 16 + h];
    __syncthreads();

    for (int it = 0; it < 4; it++) {
        int qt = it * 4 + w;
        bool act = qt < 13;
        f32x4 sc[13];
        float rs[4];
        if (act) {
            // Q A-frags straight from global: A[m=lm][k=quad*8+j]
            int qrow = qt * 16 + lm;
            int srq = qrow > 196 ? 196 : qrow;
            const u16* qp = qkv + (size_t)(srq * 64 + u) * 3072 + h * 64 + quad * 8;
            bf16x8 aq0 = *(const bf16x8*)qp;
            bf16x8 aq1 = *(const bf16x8*)(qp + 32);
            for (int kt = 0; kt < 13; kt++) {
                bf16x8 bk0 = *(const bf16x8*)&Kl[(kt * 16 + lm) * KLS + quad * 8];
                bf16x8 bk1 = *(const bf16x8*)&Kl[(kt * 16 + lm) * KLS + 32 + quad * 8];
                f32x4 s = __builtin_amdgcn_mfma_f32_16x16x32_bf16(aq0, bk0, (f32x4){0.f, 0.f, 0.f, 0.f}, 0, 0, 0);
                sc[kt] = __builtin_amdgcn_mfma_f32_16x16x32_bf16(aq1, bk1, s, 0, 0, 0);
            }
            int tk = lm;
#pragma unroll
            for (int r = 0; r < 4; r++) {
                int qr = qt * 16 + quad * 4 + r;
                int qcl = qr > 196 ? 196 : qr;
                int lq = qcl - 1;
                int qi = lq / 14, qj = lq - qi * 14;
                for (int kt = 0; kt < 13; kt++) {
                    int tkk = kt * 16 + tk;
                    float v;
                    if (tkk >= 197) v = -1e30f;
                    else {
                        v = sc[kt][r] * 0.125f;
                        if (qr >= 1 && tkk >= 1) {
                            int lk = tkk - 1;
                            int ki = lk / 14, kj = lk - ki * 14;
                            v += rpb_l[(qi - ki + 13) * 27 + (qj - kj + 13)];
                        }
                    }
                    sc[kt][r] = v;
                }
                float mx = -3e38f;
                for (int kt = 0; kt < 13; kt++) mx = fmaxf(mx, sc[kt][r]);
                mx = fmaxf(mx, __shfl_xor(mx, 1));
                mx = fmaxf(mx, __shfl_xor(mx, 2));
                mx = fmaxf(mx, __shfl_xor(mx, 4));
                mx = fmaxf(mx, __shfl_xor(mx, 8));
                float sm = 0.f;
                for (int kt = 0; kt < 13; kt++) {
                    float p = __expf(sc[kt][r] - mx);
                    sc[kt][r] = p;
                    sm += p;
                }
                sm += __shfl_xor(sm, 1);
                sm += __shfl_xor(sm, 2);
                sm += __shfl_xor(sm, 4);
                sm += __shfl_xor(sm, 8);
                rs[r] = sm;
                for (int kt = 0; kt < 13; kt++)
                    Pl[w][(quad * 4 + r) * PVS + kt * 16 + tk] = f2bf(sc[kt][r]);
            }
        }
        __syncthreads();
        if (act) {
            bf16x8 pa[7];
#pragma unroll
            for (int kc = 0; kc < 7; kc++)
                pa[kc] = *(const bf16x8*)&Pl[w][lm * PVS + kc * 32 + quad * 8];
#pragma unroll
            for (int ct = 0; ct < 4; ct++) {
                f32x4 o = (f32x4){0.f, 0.f, 0.f, 0.f};
#pragma unroll
                for (int kc = 0; kc < 7; kc++) {
                    bf16x8 vb = *(const bf16x8*)&Vt[(ct * 16 + lm) * PVS + kc * 32 + quad * 8];
                    o = __builtin_amdgcn_mfma_f32_16x16x32_bf16(pa[kc], vb, o, 0, 0, 0);
                }
#pragma unroll
                for (int r = 0; r < 4; r++) {
                    int qr = qt * 16 + quad * 4 + r;
                    if (qr < 197)
                        out[(size_t)(qr * 64 + u) * 1024 + h * 64 + ct * 16 + lm] =
                            f2bf(o[r] / rs[r]);
                }
            }
        }
        __syncthreads();
    }
}

// ---------------------------------------------------------------------------
// cls residual add (mean over frames)
// ---------------------------------------------------------------------------
__global__ __launch_bounds__(256) void add_cls(const u16* __restrict__ R, float4* __restrict__ resid4) {
    int tid = blockIdx.x * 256 + threadIdx.x;   // 2048
    int c4 = tid & 255, n = tid >> 8;
    float s0 = 0.f, s1 = 0.f, s2 = 0.f, s3 = 0.f;
#pragma unroll
    for (int t = 0; t < 8; t++) {
        ushort4 rv = *(const ushort4*)&R[(size_t)(t * 8 + n) * 1024 + c4 * 4];
        s0 += bf2f(rv.x); s1 += bf2f(rv.y); s2 += bf2f(rv.z); s3 += bf2f(rv.w);
    }
    float4 v = resid4[tid];
    v.x += s0 * 0.125f; v.y += s1 * 0.125f; v.z += s2 * 0.125f; v.w += s3 * 0.125f;
    resid4[tid] = v;
}

// ---------------------------------------------------------------------------
extern "C" void kernel_launch(void* const* d_in, const int* in_sizes, int n_in,
                              void* d_out, int out_size, void* d_ws, size_t ws_size,
                              hipStream_t stream) {
    const float* x      = (const float*)d_in[0];
    const float* pos_w  = (const float*)d_in[1];
    const float* pos_b  = (const float*)d_in[2];
    const float* ln_t_g = (const float*)d_in[3];
    const float* ln_t_b = (const float*)d_in[4];
    const float* rpb_t  = (const float*)d_in[5];
    const float* wqkv_t = (const float*)d_in[6];
    const float* bqkv_t = (const float*)d_in[7];
    const float* wo_t   = (const float*)d_in[8];
    const float* bo_t   = (const float*)d_in[9];
    const float* ln1_g  = (const float*)d_in[10];
    const float* ln1_b  = (const float*)d_in[11];
    const float* rpb_s  = (const float*)d_in[12];
    const float* wqkv_s = (const float*)d_in[13];
    const float* bqkv_s = (const float*)d_in[14];
    const float* wo_s   = (const float*)d_in[15];
    const float* bo_s   = (const float*)d_in[16];
    const float* ln2_g  = (const float*)d_in[17];
    const float* ln2_b  = (const float*)d_in[18];
    const float* fc_w   = (const float*)d_in[19];
    const float* fc_b   = (const float*)d_in[20];
    const float* proj_w = (const float*)d_in[21];
    const float* proj_b = (const float*)d_in[22];
    float* resid = (float*)d_out;

    // workspace arena (bf16 elements)
    u16* Wq_t  = (u16*)d_ws;
    u16* Wo_t  = Wq_t + 3145728;
    u16* Wq_s  = Wo_t + 1048576;
    u16* Wo_s  = Wq_s + 3145728;
    u16* Wfc   = Wo_s + 1048576;
    u16* Wpj   = Wfc  + 4194304;
    u16* Albuf = Wpj  + 4194304;          // 12608*1024
    u16* QKV   = Albuf + 12910592;        // 12608*3072
    u16* Obuf  = QKV   + 38731776;        // 12608*1024
    u16* Rbuf  = Obuf  + 12910592;        // 12608*1024
    u16* Hbuf  = QKV;                     // alias: 12552*4096 fits in QKV+Obuf
    float* wt  = (float*)QKV;             // alias: 27*1024 f32, used only by posembed

    // weight conversion (single merged launch + pos_w transpose)
    cvt_all<<<16384, 256, 0, stream>>>(
        (const float4*)wqkv_t, (ushort4*)Wq_t,
        (const float4*)wo_t,   (ushort4*)Wo_t,
        (const float4*)wqkv_s, (ushort4*)Wq_s,
        (const float4*)wo_s,   (ushort4*)Wo_s,
        (const float4*)fc_w,   (ushort4*)Wfc,
        (const float4*)proj_w, (ushort4*)Wpj);
    cvt_wt<<<108, 256, 0, stream>>>(pos_w, wt);

    // positional embedding -> resid (= xpe)
    posembed<<<12552, 256, 0, stream>>>((const float4*)x, (const float4*)wt,
                                        (const float4*)pos_b, (float4*)resid);

    // temporal attention (result NOT added to resid; feeds spatial LN only)
    ln_kernel<<<12544, 256, 0, stream>>>(resid, nullptr, ln_t_g, ln_t_b, Albuf, 0);
    gemm_bf16<<<2352, 256, 0, stream>>>(Albuf, Wq_t, bqkv_t, QKV, 12544, 3072, 1024, 0, 24);
    attn_t<<<6272, 256, 0, stream>>>(QKV, rpb_t, Obuf);
    gemm_bf16<<<784, 256, 0, stream>>>(Obuf, Wo_t, bo_t, Rbuf, 12544, 1024, 1024, 0, 8);

    // spatial attention (LN1 fuses xt_full = xpe + rt gather)
    ln_kernel<<<12608, 256, 0, stream>>>(resid, Rbuf, ln1_g, ln1_b, Albuf, 1);
    gemm_bf16<<<2376, 256, 0, stream>>>(Albuf, Wq_s, bqkv_s, QKV, 12608, 3072, 1024, 0, 24);
    attn_s<<<1024, 256, 0, stream>>>(QKV, rpb_s, Obuf);
    // wo_s with fused spatial residual scatter-add; cls rows -> Rbuf.
    gemm_wos<<<792, 256, 0, stream>>>(Obuf, Wo_s, bo_s, Rbuf, resid, 12608, 8);
    add_cls<<<8, 256, 0, stream>>>(Rbuf, (float4*)resid);

    // MLP with QuickGELU; proj on the 8-phase 256^2 kernel (K=4096 long-K
    // regime) with fused f32 residual output.
    ln_kernel<<<12552, 256, 0, stream>>>(resid, nullptr, ln2_g, ln2_b, Albuf, 2);
    gemm_bf16<<<3168, 256, 0, stream>>>(Albuf, Wfc, fc_b, Hbuf, 12552, 4096, 1024, 1, 32);
    gemm256<<<200, 512, 0, stream>>>(Hbuf, Wpj, proj_b, nullptr, resid,
                                     12552, 1024, 4096, 0, 4);
}

// Round 9
// 1054.348 us; speedup vs baseline: 1.0911x; 1.0911x over previous
//
#include <hip/hip_runtime.h>
#include <stdint.h>

typedef unsigned short u16;
typedef __attribute__((ext_vector_type(8))) __bf16 bf16x8;
typedef __attribute__((ext_vector_type(4))) float f32x4;

__device__ __forceinline__ float bf2f(u16 u) {
    return __uint_as_float(((unsigned int)u) << 16);
}
__device__ __forceinline__ u16 f2bf(float f) {
    unsigned int u = __float_as_uint(f);
    u += 0x7fffu + ((u >> 16) & 1u);   // round-to-nearest-even
    return (u16)(u >> 16);
}

// async global->LDS, 16B per lane.  LDS dest = wave-uniform base + lane*16.
__device__ __forceinline__ void gl16(const u16* g, u16* l) {
    __builtin_amdgcn_global_load_lds(
        (const __attribute__((address_space(1))) unsigned int*)(uintptr_t)g,
        (__attribute__((address_space(3))) unsigned int*)(uintptr_t)l,
        16, 0, 0);
}

// ---------------------------------------------------------------------------
// Merged f32 -> bf16 weight conversion: all 6 weight tensors in one launch.
// ---------------------------------------------------------------------------
__global__ __launch_bounds__(256) void cvt_all(const float4* __restrict__ a0, ushort4* __restrict__ o0,
                                               const float4* __restrict__ a1, ushort4* __restrict__ o1,
                                               const float4* __restrict__ a2, ushort4* __restrict__ o2,
                                               const float4* __restrict__ a3, ushort4* __restrict__ o3,
                                               const float4* __restrict__ a4, ushort4* __restrict__ o4,
                                               const float4* __restrict__ a5, ushort4* __restrict__ o5) {
    int b = blockIdx.x;
    const float4* src; ushort4* dst; int base;
    if      (b < 3072)  { src = a0; dst = o0; base = 0; }
    else if (b < 4096)  { src = a1; dst = o1; base = 3072; }
    else if (b < 7168)  { src = a2; dst = o2; base = 4096; }
    else if (b < 8192)  { src = a3; dst = o3; base = 7168; }
    else if (b < 12288) { src = a4; dst = o4; base = 8192; }
    else                { src = a5; dst = o5; base = 12288; }
    int tid = (b - base) * 256 + threadIdx.x;
    float4 v = src[tid];
    ushort4 o;
    o.x = f2bf(v.x); o.y = f2bf(v.y); o.z = f2bf(v.z); o.w = f2bf(v.w);
    dst[tid] = o;
}

// pos_w [1024][27] -> wt [27][1024] (float)
__global__ __launch_bounds__(256) void cvt_wt(const float* __restrict__ pw,
                                              float* __restrict__ wt) {
    int tid = blockIdx.x * 256 + threadIdx.x;   // 27648
    if (tid < 27648) {
        int tap = tid >> 10, c = tid & 1023;
        wt[tid] = pw[c * 27 + tap];
    }
}

// ---------------------------------------------------------------------------
// Depthwise 3x3x3 conv positional embedding, float4 vectorized.
// Spatial (di,dj) outer with hoisted base address; temporal tap inner.
// ---------------------------------------------------------------------------
__global__ __launch_bounds__(256) void posembed(const float4* __restrict__ x4,
                                                const float4* __restrict__ wt4,
                                                const float4* __restrict__ pb4,
                                                float4* __restrict__ out4) {
    int tid = blockIdx.x * 256 + threadIdx.x;   // 1569*2048 total
    float4 xv = x4[tid];
    int rf = tid >> 11;
    if (rf == 0) { out4[tid] = xv; return; }
    int c4 = tid & 255;
    int nc = tid & 2047;                        // (n<<8) + c4
    int r = rf - 1;
    int t = r & 7, l = r >> 3;
    int i = l / 14, j = l - i * 14;
    float4 pbv = pb4[c4];
    float a0 = xv.x + pbv.x, a1 = xv.y + pbv.y, a2 = xv.z + pbv.z, a3 = xv.w + pbv.w;
    const float4* wbase = wt4 + c4;
#pragma unroll
    for (int di = 0; di < 3; di++) {
        int ii = i + di - 1;
        if (ii < 0 || ii > 13) continue;
#pragma unroll
        for (int dj = 0; dj < 3; dj++) {
            int jj = j + dj - 1;
            if (jj < 0 || jj > 13) continue;
            size_t vbase = (size_t)(1 + ((ii * 14 + jj) << 3)) * 2048 + nc;
            int woff = (di * 3 + dj) * 256;
#pragma unroll
            for (int dt = 0; dt < 3; dt++) {
                int tt = t + dt - 1;
                if (tt < 0 || tt > 7) continue;
                float4 w4 = wbase[woff + dt * 2304];        // (dt*9+di*3+dj)*256
                float4 v = x4[vbase + (size_t)tt * 2048];
                a0 += w4.x * v.x; a1 += w4.y * v.y; a2 += w4.z * v.z; a3 += w4.w * v.w;
            }
        }
    }
    out4[tid] = (float4){a0, a1, a2, a3};
}

// ---------------------------------------------------------------------------
// LayerNorm with branch-specific row gather, f32 in -> bf16 out.
// ---------------------------------------------------------------------------
__global__ __launch_bounds__(256) void ln_kernel(const float* __restrict__ resid,
                                                 const u16* __restrict__ Radd,
                                                 const float* __restrict__ g,
                                                 const float* __restrict__ bb,
                                                 u16* __restrict__ out, int mode) {
    int ro = blockIdx.x;
    int tid = threadIdx.x;
    int src, n;
    long long rarow = -1;
    if (mode == 0) {
        int t = ro / 1568, b2 = ro - t * 1568;
        n = b2 / 196;
        int l = b2 - n * 196;
        src = 1 + l * 8 + t;
    } else if (mode == 1) {
        int s = ro >> 6, u = ro & 63;
        int t = u >> 3;
        n = u & 7;
        if (s == 0) src = 0;
        else { src = 1 + (s - 1) * 8 + t; rarow = (long long)(t * 1568 + n * 196 + (s - 1)); }
    } else {
        src = ro >> 3;
        n = ro & 7;
    }
    const float* xp = resid + ((size_t)src * 8 + n) * 1024 + tid * 4;
    float4 xv = *(const float4*)xp;
    float x0 = xv.x, x1 = xv.y, x2 = xv.z, x3 = xv.w;
    if (rarow >= 0) {
        const u16* rp = Radd + rarow * 1024 + tid * 4;
        x0 += bf2f(rp[0]); x1 += bf2f(rp[1]); x2 += bf2f(rp[2]); x3 += bf2f(rp[3]);
    }
    float s1 = x0 + x1 + x2 + x3;
    float s2 = x0 * x0 + x1 * x1 + x2 * x2 + x3 * x3;
#pragma unroll
    for (int off = 32; off > 0; off >>= 1) {
        s1 += __shfl_down(s1, off);
        s2 += __shfl_down(s2, off);
    }
    __shared__ float red[8];
    int lane = tid & 63, w = tid >> 6;
    if (lane == 0) { red[w] = s1; red[4 + w] = s2; }
    __syncthreads();
    float S1 = red[0] + red[1] + red[2] + red[3];
    float S2 = red[4] + red[5] + red[6] + red[7];
    float mean = S1 * (1.f / 1024.f);
    float var = S2 * (1.f / 1024.f) - mean * mean;
    float rstd = rsqrtf(var + 1e-5f);
    int c = tid * 4;
    float4 gv = *(const float4*)(g + c);
    float4 bv = *(const float4*)(bb + c);
    u16* op = out + (size_t)ro * 1024 + c;
    op[0] = f2bf((x0 - mean) * rstd * gv.x + bv.x);
    op[1] = f2bf((x1 - mean) * rstd * gv.y + bv.y);
    op[2] = f2bf((x2 - mean) * rstd * gv.z + bv.z);
    op[3] = f2bf((x3 - mean) * rstd * gv.w + bv.w);
}

// ---------------------------------------------------------------------------
// Proven 128x128 GEMM (BK=32, 2-barrier, ~2.4 blocks/CU co-resident).
// Used for the K=1024 GEMMs (QKV x2, wo_t, FC).
// ---------------------------------------------------------------------------
__global__ __launch_bounds__(256) void gemm_bf16(const u16* __restrict__ A,
                                                 const u16* __restrict__ W,
                                                 const float* __restrict__ bias,
                                                 u16* __restrict__ Co,
                                                 int M, int N, int K, int gelu,
                                                 int nx) {
    __shared__ u16 As[2][128 * 32];
    __shared__ u16 Bs[2][128 * 32];
    int tid = threadIdx.x;
    int T = gridDim.x;                       // divisible by 8
    int bid = blockIdx.x;
    int w_ = (bid & 7) * (T >> 3) + (bid >> 3);   // XCD g gets contiguous work range
    int n0 = (w_ % nx) * 128;
    int m0 = (w_ / nx) * 128;
    int lane = tid & 63, wid = tid >> 6;
    int wm = (wid >> 1) * 64, wn = (wid & 1) * 64;
    int lm = lane & 15, q = lane >> 4;

    f32x4 acc[4][4];
#pragma unroll
    for (int i = 0; i < 4; i++)
#pragma unroll
        for (int j = 0; j < 4; j++) acc[i][j] = (f32x4){0.f, 0.f, 0.f, 0.f};

    // staging map: wave w chunk c (c=0,1): lane l -> row w*32+c*16+(l>>2), col bf16 (l&3)*8
    int r0 = wid * 32 + (lane >> 2);
    int colb = (lane & 3) * 8;
    int mA0 = m0 + r0;          if (mA0 > M - 1) mA0 = M - 1;
    int mA1 = m0 + r0 + 16;     if (mA1 > M - 1) mA1 = M - 1;
    const u16* gA0 = A + (size_t)mA0 * K + colb;
    const u16* gA1 = A + (size_t)mA1 * K + colb;
    const u16* gB0 = W + (size_t)(n0 + r0) * K + colb;
    const u16* gB1 = W + (size_t)(n0 + r0 + 16) * K + colb;
    int wo = wid * 1024;

    auto loadt = [&](int b) {
        gl16(gA0, &As[b][wo]); gl16(gA1, &As[b][wo + 512]);
        gl16(gB0, &Bs[b][wo]); gl16(gB1, &Bs[b][wo + 512]);
        gA0 += 32; gA1 += 32; gB0 += 32; gB1 += 32;
    };
    auto comput = [&](int b) {
        bf16x8 af[4], bfr[4];
#pragma unroll
        for (int i = 0; i < 4; i++) af[i] = *(const bf16x8*)&As[b][(wm + i * 16 + lm) * 32 + q * 8];
#pragma unroll
        for (int j = 0; j < 4; j++) bfr[j] = *(const bf16x8*)&Bs[b][(wn + j * 16 + lm) * 32 + q * 8];
#pragma unroll
        for (int i = 0; i < 4; i++)
#pragma unroll
            for (int j = 0; j < 4; j++)
                acc[i][j] = __builtin_amdgcn_mfma_f32_16x16x32_bf16(af[i], bfr[j], acc[i][j], 0, 0, 0);
    };

    int Tt = K >> 5;                       // tiles; K is a multiple of 64
    loadt(0);
    __syncthreads();
    loadt(1); comput(0); __syncthreads();
    for (int t = 2; t + 1 < Tt; t += 2) {
        loadt(0); comput(1); __syncthreads();
        loadt(1); comput(0); __syncthreads();
    }
    comput(1);

#pragma unroll
    for (int i = 0; i < 4; i++) {
        int row_b = m0 + wm + i * 16 + q * 4;
#pragma unroll
        for (int j = 0; j < 4; j++) {
            int col = n0 + wn + j * 16 + lm;
            float bv = bias[col];
#pragma unroll
            for (int r = 0; r < 4; r++) {
                int row = row_b + r;
                if (row < M) {
                    float v = acc[i][j][r] + bv;
                    if (gelu) v = v / (1.f + __expf(-1.702f * v));  // QuickGELU
                    Co[(size_t)row * N + col] = f2bf(v);
                }
            }
        }
    }
}

// ---------------------------------------------------------------------------
// wo_s GEMM (M=12608, N=1024, K=1024) with FUSED spatial residual scatter-add:
//   rows <  64 (cls, s=0): bf16 -> Rbuf (consumed by add_cls reduction)
//   rows >= 64: resid[(1+(s-1)*8+t)*8+n][col] += acc+bias   (f32 RMW)
// ---------------------------------------------------------------------------
__global__ __launch_bounds__(256) void gemm_wos(const u16* __restrict__ A,
                                                const u16* __restrict__ W,
                                                const float* __restrict__ bias,
                                                u16* __restrict__ Rb,
                                                float* __restrict__ resid,
                                                int M, int nx) {
    const int N = 1024, K = 1024;
    __shared__ u16 As[2][128 * 32];
    __shared__ u16 Bs[2][128 * 32];
    int tid = threadIdx.x;
    int T = gridDim.x;
    int bid = blockIdx.x;
    int w_ = (bid & 7) * (T >> 3) + (bid >> 3);
    int n0 = (w_ % nx) * 128;
    int m0 = (w_ / nx) * 128;
    int lane = tid & 63, wid = tid >> 6;
    int wm = (wid >> 1) * 64, wn = (wid & 1) * 64;
    int lm = lane & 15, q = lane >> 4;

    f32x4 acc[4][4];
#pragma unroll
    for (int i = 0; i < 4; i++)
#pragma unroll
        for (int j = 0; j < 4; j++) acc[i][j] = (f32x4){0.f, 0.f, 0.f, 0.f};

    int r0 = wid * 32 + (lane >> 2);
    int colb = (lane & 3) * 8;
    int mA0 = m0 + r0;          if (mA0 > M - 1) mA0 = M - 1;
    int mA1 = m0 + r0 + 16;     if (mA1 > M - 1) mA1 = M - 1;
    const u16* gA0 = A + (size_t)mA0 * K + colb;
    const u16* gA1 = A + (size_t)mA1 * K + colb;
    const u16* gB0 = W + (size_t)(n0 + r0) * K + colb;
    const u16* gB1 = W + (size_t)(n0 + r0 + 16) * K + colb;
    int wo = wid * 1024;

    auto loadt = [&](int b) {
        gl16(gA0, &As[b][wo]); gl16(gA1, &As[b][wo + 512]);
        gl16(gB0, &Bs[b][wo]); gl16(gB1, &Bs[b][wo + 512]);
        gA0 += 32; gA1 += 32; gB0 += 32; gB1 += 32;
    };
    auto comput = [&](int b) {
        bf16x8 af[4], bfr[4];
#pragma unroll
        for (int i = 0; i < 4; i++) af[i] = *(const bf16x8*)&As[b][(wm + i * 16 + lm) * 32 + q * 8];
#pragma unroll
        for (int j = 0; j < 4; j++) bfr[j] = *(const bf16x8*)&Bs[b][(wn + j * 16 + lm) * 32 + q * 8];
#pragma unroll
        for (int i = 0; i < 4; i++)
#pragma unroll
            for (int j = 0; j < 4; j++)
                acc[i][j] = __builtin_amdgcn_mfma_f32_16x16x32_bf16(af[i], bfr[j], acc[i][j], 0, 0, 0);
    };

    int Tt = K >> 5;
    loadt(0);
    __syncthreads();
    loadt(1); comput(0); __syncthreads();
    for (int t = 2; t + 1 < Tt; t += 2) {
        loadt(0); comput(1); __syncthreads();
        loadt(1); comput(0); __syncthreads();
    }
    comput(1);

#pragma unroll
    for (int i = 0; i < 4; i++) {
        int row_b = m0 + wm + i * 16 + q * 4;
#pragma unroll
        for (int j = 0; j < 4; j++) {
            int col = n0 + wn + j * 16 + lm;
            float bv = bias[col];
#pragma unroll
            for (int r = 0; r < 4; r++) {
                int row = row_b + r;
                if (row < M) {
                    float v = acc[i][j][r] + bv;
                    if (row < 64) {
                        Rb[(size_t)row * N + col] = f2bf(v);
                    } else {
                        int s = row >> 6, u = row & 63;
                        int t2 = u >> 3, n = u & 7;
                        size_t o = ((size_t)(1 + (s - 1) * 8 + t2) * 8 + n) * 1024 + col;
                        resid[o] = resid[o] + v;
                    }
                }
            }
        }
    }
}

// ---------------------------------------------------------------------------
// bf16 MFMA GEMM, 256x256 tile, BK=64, 8-wave, 8-phase schedule.
// Used for the proj GEMM (K=4096 long-K regime) with fused f32 residual out:
//   Fout[row,col] += acc + bias
// ---------------------------------------------------------------------------
__global__ __launch_bounds__(512) void gemm256(const u16* __restrict__ A,
                                               const u16* __restrict__ W,
                                               const float* __restrict__ bias,
                                               u16* __restrict__ Co,
                                               float* __restrict__ Fout,
                                               int M, int N, int K, int gelu,
                                               int nnt) {
    __shared__ __align__(16) u16 sA[2][16384];   // [buf][256 rows x 64 cols]
    __shared__ __align__(16) u16 sB[2][16384];
    int tid = threadIdx.x;
    int wid = tid >> 6, lane = tid & 63;
    int wr = wid >> 2, wc = wid & 3;
    int lm = lane & 15, q = lane >> 4;

    // bijective XCD swizzle (m204)
    int nwg = gridDim.x, orig = blockIdx.x;
    int qq = nwg >> 3, rr = nwg & 7, xcd = orig & 7, blk = orig >> 3;
    int wg = (xcd < rr ? xcd * (qq + 1) : rr * (qq + 1) + (xcd - rr) * qq) + blk;
    int n0 = (wg % nnt) * 256, m0 = (wg / nnt) * 256;

    int NT = K >> 6, NTm1 = NT - 1;

    // staging: thread covers LDS row rl (+64/part, +128/half), chunk lane&7.
    // Global source pre-swizzled: phys chunk c of row r holds logical c^(r&7).
    int rl = wid * 8 + (lane >> 3);
    int cl = ((lane & 7) ^ (rl & 7)) * 8;
    const u16* pA[4];
    const u16* pB[4];
#pragma unroll
    for (int h2 = 0; h2 < 4; h2++) {
        int ra = m0 + h2 * 64 + rl; if (ra > M - 1) ra = M - 1;
        int rb = n0 + h2 * 64 + rl; if (rb > N - 1) rb = N - 1;
        pA[h2] = A + (size_t)ra * K + cl;
        pB[h2] = W + (size_t)rb * K + cl;
    }
    int ldst = wid * 512;

    f32x4 acc[8][4];
#pragma unroll
    for (int i = 0; i < 8; i++)
#pragma unroll
        for (int j = 0; j < 4; j++) acc[i][j] = (f32x4){0.f, 0.f, 0.f, 0.f};

    bf16x8 af[4][2];
    bf16x8 bfv[4][2];

#define STG(P, D, b, h, kt) do { \
        int _k = (kt); if (_k > NTm1) _k = NTm1; \
        gl16(P[(h) * 2] + (size_t)_k * 64, &D[b][(h) * 8192 + ldst]); \
        gl16(P[(h) * 2 + 1] + (size_t)_k * 64, &D[b][(h) * 8192 + 4096 + ldst]); \
    } while (0)
#define LDA_(b, ih) do { \
        _Pragma("unroll") for (int iq = 0; iq < 4; iq++) \
        _Pragma("unroll") for (int kk = 0; kk < 2; kk++) \
            af[iq][kk] = *(const bf16x8*)&sA[b][((ih) * 128 + wr * 64 + iq * 16 + lm) * 64 + \
                                                (((q + kk * 4) ^ (lm & 7)) * 8)]; \
    } while (0)
#define LDB_(b, jh) do { \
        _Pragma("unroll") for (int jq = 0; jq < 2; jq++) \
        _Pragma("unroll") for (int kk = 0; kk < 2; kk++) \
            bfv[(jh) * 2 + jq][kk] = *(const bf16x8*)&sB[b][((jh) * 128 + wc * 32 + jq * 16 + lm) * 64 + \
                                                            (((q + kk * 4) ^ (lm & 7)) * 8)]; \
    } while (0)
#define MMA_(ih, jh) do { \
        __builtin_amdgcn_s_setprio(1); \
        _Pragma("unroll") for (int iq = 0; iq < 4; iq++) \
        _Pragma("unroll") for (int jq = 0; jq < 2; jq++) \
        _Pragma("unroll") for (int kk = 0; kk < 2; kk++) \
            acc[(ih) * 4 + iq][(jh) * 2 + jq] = __builtin_amdgcn_mfma_f32_16x16x32_bf16( \
                af[iq][kk], bfv[(jh) * 2 + jq][kk], acc[(ih) * 4 + iq][(jh) * 2 + jq], 0, 0, 0); \
        __builtin_amdgcn_s_setprio(0); \
    } while (0)
#define BAR asm volatile("s_barrier" ::: "memory")
#define VM6 asm volatile("s_waitcnt vmcnt(6)" ::: "memory")

    // prologue: tile0 fully + tile1 {A0, B1, A1}; vmcnt(6) -> tile0 landed.
    STG(pA, sA, 0, 0, 0);
    STG(pA, sA, 0, 1, 0);
    STG(pB, sB, 0, 0, 0);
    STG(pB, sB, 0, 1, 0);
    STG(pA, sA, 1, 0, 1);
    STG(pB, sB, 1, 1, 1);
    STG(pA, sA, 1, 1, 1);
    VM6;
    BAR;

    int S = NT >> 1;
    for (int s = 0; s < S; s++) {
        int t = s * 2;
        LDA_(0, 0); LDB_(0, 0);
        STG(pB, sB, 1, 0, t + 1);
        BAR; MMA_(0, 0); BAR;
        LDB_(0, 1);
        STG(pA, sA, 0, 0, t + 2);
        BAR; MMA_(0, 1); BAR;
        LDA_(0, 1);
        STG(pB, sB, 0, 1, t + 2);
        BAR; MMA_(1, 1); BAR;
        STG(pA, sA, 0, 1, t + 2);
        VM6;
        BAR; MMA_(1, 0); BAR;
        LDA_(1, 0); LDB_(1, 0);
        STG(pB, sB, 0, 0, t + 2);
        BAR; MMA_(0, 0); BAR;
        LDB_(1, 1);
        STG(pA, sA, 1, 0, t + 3);
        BAR; MMA_(0, 1); BAR;
        LDA_(1, 1);
        STG(pB, sB, 1, 1, t + 3);
        BAR; MMA_(1, 1); BAR;
        STG(pA, sA, 1, 1, t + 3);
        VM6;
        BAR; MMA_(1, 0); BAR;
    }
    asm volatile("s_waitcnt vmcnt(0)" ::: "memory");   // drain tail prefetches

    // epilogue: bias + optional QuickGELU; bf16 store, or fused f32 resid +=
#pragma unroll
    for (int ih = 0; ih < 2; ih++)
#pragma unroll
        for (int iq = 0; iq < 4; iq++) {
            int row_b = m0 + ih * 128 + wr * 64 + iq * 16 + q * 4;
#pragma unroll
            for (int jh = 0; jh < 2; jh++)
#pragma unroll
                for (int jq = 0; jq < 2; jq++) {
                    int col = n0 + jh * 128 + wc * 32 + jq * 16 + lm;
                    float bv = bias[col];
#pragma unroll
                    for (int r = 0; r < 4; r++) {
                        int row = row_b + r;
                        if (row < M) {
                            float v = acc[ih * 4 + iq][jh * 2 + jq][r] + bv;
                            if (gelu) v = v / (1.f + __expf(-1.702f * v));  // QuickGELU
                            if (Fout) {
                                size_t o = (size_t)row * N + col;
                                Fout[o] = Fout[o] + v;
                            } else {
                                Co[(size_t)row * N + col] = f2bf(v);
                            }
                        }
                    }
                }
        }
#undef STG
#undef LDA_
#undef LDB_
#undef MMA_
#undef BAR
#undef VM6
}

// ---------------------------------------------------------------------------
// Temporal attention: S=8.  4 (b,h) pairs per 256-thread block (one wave
// each); 1568%4==0 so all four share h.  Vectorized ushort4 staging.
// ---------------------------------------------------------------------------
__global__ __launch_bounds__(256) void attn_t(const u16* __restrict__ qkv,
                                              const float* __restrict__ rpb,
                                              u16* __restrict__ out) {
    int w = threadIdx.x >> 6, d = threadIdx.x & 63;
    int bh = blockIdx.x * 4 + w;           // 6272 blocks cover 25088 pairs
    int b = bh % 1568, h = bh / 1568;
    __shared__ float qs[4][8][68], ks[4][8][68], vs[4][8][68];
    __shared__ float ps[4][8][9];
#pragma unroll
    for (int tt = 0; tt < 2; tt++) {
        int t = tt * 4 + (d >> 4);
        int c4 = (d & 15) * 4;
        size_t row = (size_t)(t * 1568 + b) * 3072 + h * 64 + c4;
        ushort4 qv = *(const ushort4*)(qkv + row);
        ushort4 kv = *(const ushort4*)(qkv + row + 1024);
        ushort4 vv = *(const ushort4*)(qkv + row + 2048);
        qs[w][t][c4 + 0] = bf2f(qv.x) * 0.125f; qs[w][t][c4 + 1] = bf2f(qv.y) * 0.125f;
        qs[w][t][c4 + 2] = bf2f(qv.z) * 0.125f; qs[w][t][c4 + 3] = bf2f(qv.w) * 0.125f;
        ks[w][t][c4 + 0] = bf2f(kv.x); ks[w][t][c4 + 1] = bf2f(kv.y);
        ks[w][t][c4 + 2] = bf2f(kv.z); ks[w][t][c4 + 3] = bf2f(kv.w);
        vs[w][t][c4 + 0] = bf2f(vv.x); vs[w][t][c4 + 1] = bf2f(vv.y);
        vs[w][t][c4 + 2] = bf2f(vv.z); vs[w][t][c4 + 3] = bf2f(vv.w);
    }
    __syncthreads();
    int tq = d >> 3, tk = d & 7;
    float s = rpb[(tq - tk + 7) * 16 + h];
#pragma unroll
    for (int dd = 0; dd < 64; dd++) s += qs[w][tq][dd] * ks[w][tk][dd];
    float mx = s;
    mx = fmaxf(mx, __shfl_xor(mx, 1));
    mx = fmaxf(mx, __shfl_xor(mx, 2));
    mx = fmaxf(mx, __shfl_xor(mx, 4));
    float p = __expf(s - mx);
    float su = p;
    su += __shfl_xor(su, 1);
    su += __shfl_xor(su, 2);
    su += __shfl_xor(su, 4);
    ps[w][tq][tk] = p / su;
    __syncthreads();
#pragma unroll
    for (int t2 = 0; t2 < 8; t2++) {
        float o = 0.f;
#pragma unroll
        for (int k2 = 0; k2 < 8; k2++) o += ps[w][t2][k2] * vs[w][k2][d];
        out[(size_t)(t2 * 1568 + b) * 1024 + h * 64 + d] = f2bf(o);
    }
}

// ---------------------------------------------------------------------------
// Spatial attention, MFMA version.  S'=197 (13 q-tiles of 16, 13 k-tiles),
// one block(256)=4 waves per (u=t*8+n, h).
// v2: no per-phase barriers (Pl is per-wave-private; Kl/Vt read-only after
// the staging barrier -> all QK/softmax/PV deps are intra-wave, ordered by
// compiler lgkmcnt + in-order DS).  P tile halved to [16][136] with two-phase
// PV (cols 0..127 then 128..223, o[] accumulated in registers) -> LDS total
// 80000 B <= 80 KiB -> 2 blocks/CU (was 92 KiB -> 1 block/CU).
// ---------------------------------------------------------------------------
#define KLS 72
#define PVS 232
#define PLW 136
__global__ __launch_bounds__(256) void attn_s(const u16* __restrict__ qkv,
                                              const float* __restrict__ rpb,
                                              u16* __restrict__ out) {
    __shared__ u16 Kl[208 * KLS];        // [key][feat], rows 197..207 zero
    __shared__ u16 Vt[64 * PVS];         // [feat][key], cols 197..231 zero
    __shared__ u16 Pl[4][16 * PLW];      // per-wave half-P tile
    __shared__ float rpb_l[736];
    int blk = blockIdx.x;
    int u = blk & 63, h = blk >> 6;
    int tid = threadIdx.x;
    int w = tid >> 6, lane = tid & 63;
    int lm = lane & 15, quad = lane >> 4;

    // ---- stage K, V^T ----
    for (int idx = tid; idx < 197 * 8; idx += 256) {
        int s = idx >> 3, c8 = idx & 7;
        const u16* gp = qkv + (size_t)(s * 64 + u) * 3072 + h * 64 + c8 * 8;
        uint4 kv = *(const uint4*)(gp + 1024);
        uint4 vv = *(const uint4*)(gp + 2048);
        *(uint4*)&Kl[s * KLS + c8 * 8] = kv;
        const u16* vp = (const u16*)&vv;
#pragma unroll
        for (int j = 0; j < 8; j++) Vt[(c8 * 8 + j) * PVS + s] = vp[j];
    }
    for (int i = tid; i < 11 * KLS; i += 256) Kl[197 * KLS + i] = 0;
    for (int i = tid; i < 64 * 35; i += 256) {
        int dd = i / 35, c = 197 + (i - dd * 35);
        Vt[dd * PVS + c] = 0;
    }
    for (int i = tid; i < 729; i += 256) rpb_l[i] = rpb[i * 16 + h];
    __syncthreads();

    for (int qt = w; qt < 13; qt += 4) {
        f32x4 sc[13];
        float rs[4];
        // Q A-frags straight from global: A[m=lm][k=quad*8+j]
        int qrow = qt * 16 + lm;
        int srq = qrow > 196 ? 196 : qrow;
        const u16* qp = qkv + (size_t)(srq * 64 + u) * 3072 + h * 64 + quad * 8;
        bf16x8 aq0 = *(const bf16x8*)qp;
        bf16x8 aq1 = *(const bf16x8*)(qp + 32);
        for (int kt = 0; kt < 13; kt++) {
            bf16x8 bk0 = *(const bf16x8*)&Kl[(kt * 16 + lm) * KLS + quad * 8];
            bf16x8 bk1 = *(const bf16x8*)&Kl[(kt * 16 + lm) * KLS + 32 + quad * 8];
            f32x4 s = __builtin_amdgcn_mfma_f32_16x16x32_bf16(aq0, bk0, (f32x4){0.f, 0.f, 0.f, 0.f}, 0, 0, 0);
            sc[kt] = __builtin_amdgcn_mfma_f32_16x16x32_bf16(aq1, bk1, s, 0, 0, 0);
        }
        int tk = lm;
#pragma unroll
        for (int r = 0; r < 4; r++) {
            int qr = qt * 16 + quad * 4 + r;
            int qcl = qr > 196 ? 196 : qr;
            int lq = qcl - 1;
            int qi = lq / 14, qj = lq - qi * 14;
            for (int kt = 0; kt < 13; kt++) {
                int tkk = kt * 16 + tk;
                float v;
                if (tkk >= 197) v = -1e30f;
                else {
                    v = sc[kt][r] * 0.125f;
                    if (qr >= 1 && tkk >= 1) {
                        int lk = tkk - 1;
                        int ki = lk / 14, kj = lk - ki * 14;
                        v += rpb_l[(qi - ki + 13) * 27 + (qj - kj + 13)];
                    }
                }
                sc[kt][r] = v;
            }
            float mx = -3e38f;
            for (int kt = 0; kt < 13; kt++) mx = fmaxf(mx, sc[kt][r]);
            mx = fmaxf(mx, __shfl_xor(mx, 1));
            mx = fmaxf(mx, __shfl_xor(mx, 2));
            mx = fmaxf(mx, __shfl_xor(mx, 4));
            mx = fmaxf(mx, __shfl_xor(mx, 8));
            float sm = 0.f;
            for (int kt = 0; kt < 13; kt++) {
                float p = __expf(sc[kt][r] - mx);
                sc[kt][r] = p;
                sm += p;
            }
            sm += __shfl_xor(sm, 1);
            sm += __shfl_xor(sm, 2);
            sm += __shfl_xor(sm, 4);
            sm += __shfl_xor(sm, 8);
            rs[r] = sm;
            // phase A: P cols 0..127 (kt 0..7)
            for (int kt = 0; kt < 8; kt++)
                Pl[w][(quad * 4 + r) * PLW + kt * 16 + tk] = f2bf(sc[kt][r]);
        }
        // phase A PV: kc 0..3 over P cols 0..127 (intra-wave dep; lgkmcnt)
        bf16x8 pa[7];
#pragma unroll
        for (int kc = 0; kc < 4; kc++)
            pa[kc] = *(const bf16x8*)&Pl[w][lm * PLW + kc * 32 + quad * 8];
        f32x4 o[4];
#pragma unroll
        for (int ct = 0; ct < 4; ct++) {
            o[ct] = (f32x4){0.f, 0.f, 0.f, 0.f};
#pragma unroll
            for (int kc = 0; kc < 4; kc++) {
                bf16x8 vb = *(const bf16x8*)&Vt[(ct * 16 + lm) * PVS + kc * 32 + quad * 8];
                o[ct] = __builtin_amdgcn_mfma_f32_16x16x32_bf16(pa[kc], vb, o[ct], 0, 0, 0);
            }
        }
        // phase B: overwrite P tile with cols 128..223 (kt 8..12 + zero pad)
#pragma unroll
        for (int r = 0; r < 4; r++)
            for (int kt = 8; kt < 13; kt++)
                Pl[w][(quad * 4 + r) * PLW + (kt - 8) * 16 + tk] = f2bf(sc[kt][r]);
        {   // zero local cols 80..95 (= global 208..223), overwritten by phase A
            int zr = lane >> 2, zc = 80 + (lane & 3) * 4;
            *(ushort4*)&Pl[w][zr * PLW + zc] = (ushort4){0, 0, 0, 0};
        }
#pragma unroll
        for (int kc = 4; kc < 7; kc++)
            pa[kc] = *(const bf16x8*)&Pl[w][lm * PLW + (kc - 4) * 32 + quad * 8];
#pragma unroll
        for (int ct = 0; ct < 4; ct++) {
#pragma unroll
            for (int kc = 4; kc < 7; kc++) {
                bf16x8 vb = *(const bf16x8*)&Vt[(ct * 16 + lm) * PVS + kc * 32 + quad * 8];
                o[ct] = __builtin_amdgcn_mfma_f32_16x16x32_bf16(pa[kc], vb, o[ct], 0, 0, 0);
            }
        }
        // store
#pragma unroll
        for (int ct = 0; ct < 4; ct++)
#pragma unroll
            for (int r = 0; r < 4; r++) {
                int qr = qt * 16 + quad * 4 + r;
                if (qr < 197)
                    out[(size_t)(qr * 64 + u) * 1024 + h * 64 + ct * 16 + lm] =
                        f2bf(o[ct][r] / rs[r]);
            }
    }
}

// ---------------------------------------------------------------------------
// cls residual add (mean over frames)
// ---------------------------------------------------------------------------
__global__ __launch_bounds__(256) void add_cls(const u16* __restrict__ R, float4* __restrict__ resid4) {
    int tid = blockIdx.x * 256 + threadIdx.x;   // 2048
    int c4 = tid & 255, n = tid >> 8;
    float s0 = 0.f, s1 = 0.f, s2 = 0.f, s3 = 0.f;
#pragma unroll
    for (int t = 0; t < 8; t++) {
        ushort4 rv = *(const ushort4*)&R[(size_t)(t * 8 + n) * 1024 + c4 * 4];
        s0 += bf2f(rv.x); s1 += bf2f(rv.y); s2 += bf2f(rv.z); s3 += bf2f(rv.w);
    }
    float4 v = resid4[tid];
    v.x += s0 * 0.125f; v.y += s1 * 0.125f; v.z += s2 * 0.125f; v.w += s3 * 0.125f;
    resid4[tid] = v;
}

// ---------------------------------------------------------------------------
extern "C" void kernel_launch(void* const* d_in, const int* in_sizes, int n_in,
                              void* d_out, int out_size, void* d_ws, size_t ws_size,
                              hipStream_t stream) {
    const float* x      = (const float*)d_in[0];
    const float* pos_w  = (const float*)d_in[1];
    const float* pos_b  = (const float*)d_in[2];
    const float* ln_t_g = (const float*)d_in[3];
    const float* ln_t_b = (const float*)d_in[4];
    const float* rpb_t  = (const float*)d_in[5];
    const float* wqkv_t = (const float*)d_in[6];
    const float* bqkv_t = (const float*)d_in[7];
    const float* wo_t   = (const float*)d_in[8];
    const float* bo_t   = (const float*)d_in[9];
    const float* ln1_g  = (const float*)d_in[10];
    const float* ln1_b  = (const float*)d_in[11];
    const float* rpb_s  = (const float*)d_in[12];
    const float* wqkv_s = (const float*)d_in[13];
    const float* bqkv_s = (const float*)d_in[14];
    const float* wo_s   = (const float*)d_in[15];
    const float* bo_s   = (const float*)d_in[16];
    const float* ln2_g  = (const float*)d_in[17];
    const float* ln2_b  = (const float*)d_in[18];
    const float* fc_w   = (const float*)d_in[19];
    const float* fc_b   = (const float*)d_in[20];
    const float* proj_w = (const float*)d_in[21];
    const float* proj_b = (const float*)d_in[22];
    float* resid = (float*)d_out;

    // workspace arena (bf16 elements)
    u16* Wq_t  = (u16*)d_ws;
    u16* Wo_t  = Wq_t + 3145728;
    u16* Wq_s  = Wo_t + 1048576;
    u16* Wo_s  = Wq_s + 3145728;
    u16* Wfc   = Wo_s + 1048576;
    u16* Wpj   = Wfc  + 4194304;
    u16* Albuf = Wpj  + 4194304;          // 12608*1024
    u16* QKV   = Albuf + 12910592;        // 12608*3072
    u16* Obuf  = QKV   + 38731776;        // 12608*1024
    u16* Rbuf  = Obuf  + 12910592;        // 12608*1024
    u16* Hbuf  = QKV;                     // alias: 12552*4096 fits in QKV+Obuf
    float* wt  = (float*)QKV;             // alias: 27*1024 f32, used only by posembed

    // weight conversion (single merged launch + pos_w transpose)
    cvt_all<<<16384, 256, 0, stream>>>(
        (const float4*)wqkv_t, (ushort4*)Wq_t,
        (const float4*)wo_t,   (ushort4*)Wo_t,
        (const float4*)wqkv_s, (ushort4*)Wq_s,
        (const float4*)wo_s,   (ushort4*)Wo_s,
        (const float4*)fc_w,   (ushort4*)Wfc,
        (const float4*)proj_w, (ushort4*)Wpj);
    cvt_wt<<<108, 256, 0, stream>>>(pos_w, wt);

    // positional embedding -> resid (= xpe)
    posembed<<<12552, 256, 0, stream>>>((const float4*)x, (const float4*)wt,
                                        (const float4*)pos_b, (float4*)resid);

    // temporal attention (result NOT added to resid; feeds spatial LN only)
    ln_kernel<<<12544, 256, 0, stream>>>(resid, nullptr, ln_t_g, ln_t_b, Albuf, 0);
    gemm_bf16<<<2352, 256, 0, stream>>>(Albuf, Wq_t, bqkv_t, QKV, 12544, 3072, 1024, 0, 24);
    attn_t<<<6272, 256, 0, stream>>>(QKV, rpb_t, Obuf);
    gemm_bf16<<<784, 256, 0, stream>>>(Obuf, Wo_t, bo_t, Rbuf, 12544, 1024, 1024, 0, 8);

    // spatial attention (LN1 fuses xt_full = xpe + rt gather)
    ln_kernel<<<12608, 256, 0, stream>>>(resid, Rbuf, ln1_g, ln1_b, Albuf, 1);
    gemm_bf16<<<2376, 256, 0, stream>>>(Albuf, Wq_s, bqkv_s, QKV, 12608, 3072, 1024, 0, 24);
    attn_s<<<1024, 256, 0, stream>>>(QKV, rpb_s, Obuf);
    // wo_s with fused spatial residual scatter-add; cls rows -> Rbuf.
    gemm_wos<<<792, 256, 0, stream>>>(Obuf, Wo_s, bo_s, Rbuf, resid, 12608, 8);
    add_cls<<<8, 256, 0, stream>>>(Rbuf, (float4*)resid);

    // MLP with QuickGELU; proj on the 8-phase 256^2 kernel (K=4096 long-K
    // regime) with fused f32 residual output.
    ln_kernel<<<12552, 256, 0, stream>>>(resid, nullptr, ln2_g, ln2_b, Albuf, 2);
    gemm_bf16<<<3168, 256, 0, stream>>>(Albuf, Wfc, fc_b, Hbuf, 12552, 4096, 1024, 1, 32);
    gemm256<<<200, 512, 0, stream>>>(Hbuf, Wpj, proj_b, nullptr, resid,
                                     12552, 1024, 4096, 0, 4);
}

// Round 10
// 1044.346 us; speedup vs baseline: 1.1015x; 1.0096x over previous
//
#include <hip/hip_runtime.h>
#include <stdint.h>

typedef unsigned short u16;
typedef __attribute__((ext_vector_type(8))) __bf16 bf16x8;
typedef __attribute__((ext_vector_type(4))) float f32x4;

__device__ __forceinline__ float bf2f(u16 u) {
    return __uint_as_float(((unsigned int)u) << 16);
}
__device__ __forceinline__ u16 f2bf(float f) {
    unsigned int u = __float_as_uint(f);
    u += 0x7fffu + ((u >> 16) & 1u);   // round-to-nearest-even
    return (u16)(u >> 16);
}

// async global->LDS, 16B per lane.  LDS dest = wave-uniform base + lane*16.
__device__ __forceinline__ void gl16(const u16* g, u16* l) {
    __builtin_amdgcn_global_load_lds(
        (const __attribute__((address_space(1))) unsigned int*)(uintptr_t)g,
        (__attribute__((address_space(3))) unsigned int*)(uintptr_t)l,
        16, 0, 0);
}

// ---------------------------------------------------------------------------
// Merged f32 -> bf16 weight conversion + pos_w transpose, one launch.
// Block ranges (each block = 256 float4): wqkv_t 3072 | wo_t 1024 |
// wqkv_s 3072 | wo_s 1024 | fc 4096 | proj 4096 | pos_w-transpose 108
// ---------------------------------------------------------------------------
__global__ __launch_bounds__(256) void cvt_all(const float4* __restrict__ a0, ushort4* __restrict__ o0,
                                               const float4* __restrict__ a1, ushort4* __restrict__ o1,
                                               const float4* __restrict__ a2, ushort4* __restrict__ o2,
                                               const float4* __restrict__ a3, ushort4* __restrict__ o3,
                                               const float4* __restrict__ a4, ushort4* __restrict__ o4,
                                               const float4* __restrict__ a5, ushort4* __restrict__ o5,
                                               const float* __restrict__ pw, float* __restrict__ wt) {
    int b = blockIdx.x;
    if (b >= 16384) {                       // pos_w [1024][27] -> wt [27][1024]
        int tid = (b - 16384) * 256 + threadIdx.x;   // 27648
        if (tid < 27648) {
            int tap = tid >> 10, c = tid & 1023;
            wt[tid] = pw[c * 27 + tap];
        }
        return;
    }
    const float4* src; ushort4* dst; int base;
    if      (b < 3072)  { src = a0; dst = o0; base = 0; }
    else if (b < 4096)  { src = a1; dst = o1; base = 3072; }
    else if (b < 7168)  { src = a2; dst = o2; base = 4096; }
    else if (b < 8192)  { src = a3; dst = o3; base = 7168; }
    else if (b < 12288) { src = a4; dst = o4; base = 8192; }
    else                { src = a5; dst = o5; base = 12288; }
    int tid = (b - base) * 256 + threadIdx.x;
    float4 v = src[tid];
    ushort4 o;
    o.x = f2bf(v.x); o.y = f2bf(v.y); o.z = f2bf(v.z); o.w = f2bf(v.w);
    dst[tid] = o;
}

// ---------------------------------------------------------------------------
// Depthwise 3x3x3 conv positional embedding, float4 vectorized.
// Spatial (di,dj) outer with hoisted base address; temporal tap inner.
// ---------------------------------------------------------------------------
__global__ __launch_bounds__(256) void posembed(const float4* __restrict__ x4,
                                                const float4* __restrict__ wt4,
                                                const float4* __restrict__ pb4,
                                                float4* __restrict__ out4) {
    int tid = blockIdx.x * 256 + threadIdx.x;   // 1569*2048 total
    float4 xv = x4[tid];
    int rf = tid >> 11;
    if (rf == 0) { out4[tid] = xv; return; }
    int c4 = tid & 255;
    int nc = tid & 2047;                        // (n<<8) + c4
    int r = rf - 1;
    int t = r & 7, l = r >> 3;
    int i = l / 14, j = l - i * 14;
    float4 pbv = pb4[c4];
    float a0 = xv.x + pbv.x, a1 = xv.y + pbv.y, a2 = xv.z + pbv.z, a3 = xv.w + pbv.w;
    const float4* wbase = wt4 + c4;
#pragma unroll
    for (int di = 0; di < 3; di++) {
        int ii = i + di - 1;
        if (ii < 0 || ii > 13) continue;
#pragma unroll
        for (int dj = 0; dj < 3; dj++) {
            int jj = j + dj - 1;
            if (jj < 0 || jj > 13) continue;
            size_t vbase = (size_t)(1 + ((ii * 14 + jj) << 3)) * 2048 + nc;
            int woff = (di * 3 + dj) * 256;
#pragma unroll
            for (int dt = 0; dt < 3; dt++) {
                int tt = t + dt - 1;
                if (tt < 0 || tt > 7) continue;
                float4 w4 = wbase[woff + dt * 2304];        // (dt*9+di*3+dj)*256
                float4 v = x4[vbase + (size_t)tt * 2048];
                a0 += w4.x * v.x; a1 += w4.y * v.y; a2 += w4.z * v.z; a3 += w4.w * v.w;
            }
        }
    }
    out4[tid] = (float4){a0, a1, a2, a3};
}

// ---------------------------------------------------------------------------
// LayerNorm with branch-specific row gather, f32 in -> bf16 out.
// ---------------------------------------------------------------------------
__global__ __launch_bounds__(256) void ln_kernel(const float* __restrict__ resid,
                                                 const u16* __restrict__ Radd,
                                                 const float* __restrict__ g,
                                                 const float* __restrict__ bb,
                                                 u16* __restrict__ out, int mode) {
    int ro = blockIdx.x;
    int tid = threadIdx.x;
    int src, n;
    long long rarow = -1;
    if (mode == 0) {
        int t = ro / 1568, b2 = ro - t * 1568;
        n = b2 / 196;
        int l = b2 - n * 196;
        src = 1 + l * 8 + t;
    } else if (mode == 1) {
        int s = ro >> 6, u = ro & 63;
        int t = u >> 3;
        n = u & 7;
        if (s == 0) src = 0;
        else { src = 1 + (s - 1) * 8 + t; rarow = (long long)(t * 1568 + n * 196 + (s - 1)); }
    } else {
        src = ro >> 3;
        n = ro & 7;
    }
    const float* xp = resid + ((size_t)src * 8 + n) * 1024 + tid * 4;
    float4 xv = *(const float4*)xp;
    float x0 = xv.x, x1 = xv.y, x2 = xv.z, x3 = xv.w;
    if (rarow >= 0) {
        const u16* rp = Radd + rarow * 1024 + tid * 4;
        x0 += bf2f(rp[0]); x1 += bf2f(rp[1]); x2 += bf2f(rp[2]); x3 += bf2f(rp[3]);
    }
    float s1 = x0 + x1 + x2 + x3;
    float s2 = x0 * x0 + x1 * x1 + x2 * x2 + x3 * x3;
#pragma unroll
    for (int off = 32; off > 0; off >>= 1) {
        s1 += __shfl_down(s1, off);
        s2 += __shfl_down(s2, off);
    }
    __shared__ float red[8];
    int lane = tid & 63, w = tid >> 6;
    if (lane == 0) { red[w] = s1; red[4 + w] = s2; }
    __syncthreads();
    float S1 = red[0] + red[1] + red[2] + red[3];
    float S2 = red[4] + red[5] + red[6] + red[7];
    float mean = S1 * (1.f / 1024.f);
    float var = S2 * (1.f / 1024.f) - mean * mean;
    float rstd = rsqrtf(var + 1e-5f);
    int c = tid * 4;
    float4 gv = *(const float4*)(g + c);
    float4 bv = *(const float4*)(bb + c);
    u16* op = out + (size_t)ro * 1024 + c;
    op[0] = f2bf((x0 - mean) * rstd * gv.x + bv.x);
    op[1] = f2bf((x1 - mean) * rstd * gv.y + bv.y);
    op[2] = f2bf((x2 - mean) * rstd * gv.z + bv.z);
    op[3] = f2bf((x3 - mean) * rstd * gv.w + bv.w);
}

// ---------------------------------------------------------------------------
// Proven 128x128 GEMM (BK=32, 2-barrier, ~2.4 blocks/CU co-resident).
// Used for the K=1024 GEMMs (QKV x2, wo_t, FC).
// ---------------------------------------------------------------------------
__global__ __launch_bounds__(256) void gemm_bf16(const u16* __restrict__ A,
                                                 const u16* __restrict__ W,
                                                 const float* __restrict__ bias,
                                                 u16* __restrict__ Co,
                                                 int M, int N, int K, int gelu,
                                                 int nx) {
    __shared__ u16 As[2][128 * 32];
    __shared__ u16 Bs[2][128 * 32];
    int tid = threadIdx.x;
    int T = gridDim.x;                       // divisible by 8
    int bid = blockIdx.x;
    int w_ = (bid & 7) * (T >> 3) + (bid >> 3);   // XCD g gets contiguous work range
    int n0 = (w_ % nx) * 128;
    int m0 = (w_ / nx) * 128;
    int lane = tid & 63, wid = tid >> 6;
    int wm = (wid >> 1) * 64, wn = (wid & 1) * 64;
    int lm = lane & 15, q = lane >> 4;

    f32x4 acc[4][4];
#pragma unroll
    for (int i = 0; i < 4; i++)
#pragma unroll
        for (int j = 0; j < 4; j++) acc[i][j] = (f32x4){0.f, 0.f, 0.f, 0.f};

    // staging map: wave w chunk c (c=0,1): lane l -> row w*32+c*16+(l>>2), col bf16 (l&3)*8
    int r0 = wid * 32 + (lane >> 2);
    int colb = (lane & 3) * 8;
    int mA0 = m0 + r0;          if (mA0 > M - 1) mA0 = M - 1;
    int mA1 = m0 + r0 + 16;     if (mA1 > M - 1) mA1 = M - 1;
    const u16* gA0 = A + (size_t)mA0 * K + colb;
    const u16* gA1 = A + (size_t)mA1 * K + colb;
    const u16* gB0 = W + (size_t)(n0 + r0) * K + colb;
    const u16* gB1 = W + (size_t)(n0 + r0 + 16) * K + colb;
    int wo = wid * 1024;

    auto loadt = [&](int b) {
        gl16(gA0, &As[b][wo]); gl16(gA1, &As[b][wo + 512]);
        gl16(gB0, &Bs[b][wo]); gl16(gB1, &Bs[b][wo + 512]);
        gA0 += 32; gA1 += 32; gB0 += 32; gB1 += 32;
    };
    auto comput = [&](int b) {
        bf16x8 af[4], bfr[4];
#pragma unroll
        for (int i = 0; i < 4; i++) af[i] = *(const bf16x8*)&As[b][(wm + i * 16 + lm) * 32 + q * 8];
#pragma unroll
        for (int j = 0; j < 4; j++) bfr[j] = *(const bf16x8*)&Bs[b][(wn + j * 16 + lm) * 32 + q * 8];
#pragma unroll
        for (int i = 0; i < 4; i++)
#pragma unroll
            for (int j = 0; j < 4; j++)
                acc[i][j] = __builtin_amdgcn_mfma_f32_16x16x32_bf16(af[i], bfr[j], acc[i][j], 0, 0, 0);
    };

    int Tt = K >> 5;                       // tiles; K is a multiple of 64
    loadt(0);
    __syncthreads();
    loadt(1); comput(0); __syncthreads();
    for (int t = 2; t + 1 < Tt; t += 2) {
        loadt(0); comput(1); __syncthreads();
        loadt(1); comput(0); __syncthreads();
    }
    comput(1);

#pragma unroll
    for (int i = 0; i < 4; i++) {
        int row_b = m0 + wm + i * 16 + q * 4;
#pragma unroll
        for (int j = 0; j < 4; j++) {
            int col = n0 + wn + j * 16 + lm;
            float bv = bias[col];
#pragma unroll
            for (int r = 0; r < 4; r++) {
                int row = row_b + r;
                if (row < M) {
                    float v = acc[i][j][r] + bv;
                    if (gelu) v = v / (1.f + __expf(-1.702f * v));  // QuickGELU
                    Co[(size_t)row * N + col] = f2bf(v);
                }
            }
        }
    }
}

// ---------------------------------------------------------------------------
// wo_s GEMM (M=12608, N=1024, K=1024) with FUSED residual updates:
//   rows <  64 (cls, s=0): atomicAdd 0.125*v into resid[n*1024+col]
//                          (frame-mean of the cls token, replaces add_cls)
//   rows >= 64: resid[(1+(s-1)*8+t)*8+n][col] += acc+bias   (f32 RMW)
// ---------------------------------------------------------------------------
__global__ __launch_bounds__(256) void gemm_wos(const u16* __restrict__ A,
                                                const u16* __restrict__ W,
                                                const float* __restrict__ bias,
                                                float* __restrict__ resid,
                                                int M, int nx) {
    const int N = 1024, K = 1024;
    __shared__ u16 As[2][128 * 32];
    __shared__ u16 Bs[2][128 * 32];
    int tid = threadIdx.x;
    int T = gridDim.x;
    int bid = blockIdx.x;
    int w_ = (bid & 7) * (T >> 3) + (bid >> 3);
    int n0 = (w_ % nx) * 128;
    int m0 = (w_ / nx) * 128;
    int lane = tid & 63, wid = tid >> 6;
    int wm = (wid >> 1) * 64, wn = (wid & 1) * 64;
    int lm = lane & 15, q = lane >> 4;

    f32x4 acc[4][4];
#pragma unroll
    for (int i = 0; i < 4; i++)
#pragma unroll
        for (int j = 0; j < 4; j++) acc[i][j] = (f32x4){0.f, 0.f, 0.f, 0.f};

    int r0 = wid * 32 + (lane >> 2);
    int colb = (lane & 3) * 8;
    int mA0 = m0 + r0;          if (mA0 > M - 1) mA0 = M - 1;
    int mA1 = m0 + r0 + 16;     if (mA1 > M - 1) mA1 = M - 1;
    const u16* gA0 = A + (size_t)mA0 * K + colb;
    const u16* gA1 = A + (size_t)mA1 * K + colb;
    const u16* gB0 = W + (size_t)(n0 + r0) * K + colb;
    const u16* gB1 = W + (size_t)(n0 + r0 + 16) * K + colb;
    int wo = wid * 1024;

    auto loadt = [&](int b) {
        gl16(gA0, &As[b][wo]); gl16(gA1, &As[b][wo + 512]);
        gl16(gB0, &Bs[b][wo]); gl16(gB1, &Bs[b][wo + 512]);
        gA0 += 32; gA1 += 32; gB0 += 32; gB1 += 32;
    };
    auto comput = [&](int b) {
        bf16x8 af[4], bfr[4];
#pragma unroll
        for (int i = 0; i < 4; i++) af[i] = *(const bf16x8*)&As[b][(wm + i * 16 + lm) * 32 + q * 8];
#pragma unroll
        for (int j = 0; j < 4; j++) bfr[j] = *(const bf16x8*)&Bs[b][(wn + j * 16 + lm) * 32 + q * 8];
#pragma unroll
        for (int i = 0; i < 4; i++)
#pragma unroll
            for (int j = 0; j < 4; j++)
                acc[i][j] = __builtin_amdgcn_mfma_f32_16x16x32_bf16(af[i], bfr[j], acc[i][j], 0, 0, 0);
    };

    int Tt = K >> 5;
    loadt(0);
    __syncthreads();
    loadt(1); comput(0); __syncthreads();
    for (int t = 2; t + 1 < Tt; t += 2) {
        loadt(0); comput(1); __syncthreads();
        loadt(1); comput(0); __syncthreads();
    }
    comput(1);

#pragma unroll
    for (int i = 0; i < 4; i++) {
        int row_b = m0 + wm + i * 16 + q * 4;
#pragma unroll
        for (int j = 0; j < 4; j++) {
            int col = n0 + wn + j * 16 + lm;
            float bv = bias[col];
#pragma unroll
            for (int r = 0; r < 4; r++) {
                int row = row_b + r;
                if (row < M) {
                    float v = acc[i][j][r] + bv;
                    if (row < 64) {
                        // cls frame-mean: row = t*8+n, contribute v/8 to resid[n]
                        int n = row & 7;
                        atomicAdd(&resid[(size_t)n * 1024 + col], 0.125f * v);
                    } else {
                        int s = row >> 6, u = row & 63;
                        int t2 = u >> 3, n = u & 7;
                        size_t o = ((size_t)(1 + (s - 1) * 8 + t2) * 8 + n) * 1024 + col;
                        resid[o] = resid[o] + v;
                    }
                }
            }
        }
    }
}

// ---------------------------------------------------------------------------
// bf16 MFMA GEMM, 256x256 tile, BK=64, 8-wave, 8-phase schedule.
// Used for the proj GEMM (K=4096 long-K regime) with fused f32 residual out:
//   Fout[row,col] += acc + bias
// ---------------------------------------------------------------------------
__global__ __launch_bounds__(512) void gemm256(const u16* __restrict__ A,
                                               const u16* __restrict__ W,
                                               const float* __restrict__ bias,
                                               u16* __restrict__ Co,
                                               float* __restrict__ Fout,
                                               int M, int N, int K, int gelu,
                                               int nnt) {
    __shared__ __align__(16) u16 sA[2][16384];   // [buf][256 rows x 64 cols]
    __shared__ __align__(16) u16 sB[2][16384];
    int tid = threadIdx.x;
    int wid = tid >> 6, lane = tid & 63;
    int wr = wid >> 2, wc = wid & 3;
    int lm = lane & 15, q = lane >> 4;

    // bijective XCD swizzle (m204)
    int nwg = gridDim.x, orig = blockIdx.x;
    int qq = nwg >> 3, rr = nwg & 7, xcd = orig & 7, blk = orig >> 3;
    int wg = (xcd < rr ? xcd * (qq + 1) : rr * (qq + 1) + (xcd - rr) * qq) + blk;
    int n0 = (wg % nnt) * 256, m0 = (wg / nnt) * 256;

    int NT = K >> 6, NTm1 = NT - 1;

    // staging: thread covers LDS row rl (+64/part, +128/half), chunk lane&7.
    // Global source pre-swizzled: phys chunk c of row r holds logical c^(r&7).
    int rl = wid * 8 + (lane >> 3);
    int cl = ((lane & 7) ^ (rl & 7)) * 8;
    const u16* pA[4];
    const u16* pB[4];
#pragma unroll
    for (int h2 = 0; h2 < 4; h2++) {
        int ra = m0 + h2 * 64 + rl; if (ra > M - 1) ra = M - 1;
        int rb = n0 + h2 * 64 + rl; if (rb > N - 1) rb = N - 1;
        pA[h2] = A + (size_t)ra * K + cl;
        pB[h2] = W + (size_t)rb * K + cl;
    }
    int ldst = wid * 512;

    f32x4 acc[8][4];
#pragma unroll
    for (int i = 0; i < 8; i++)
#pragma unroll
        for (int j = 0; j < 4; j++) acc[i][j] = (f32x4){0.f, 0.f, 0.f, 0.f};

    bf16x8 af[4][2];
    bf16x8 bfv[4][2];

#define STG(P, D, b, h, kt) do { \
        int _k = (kt); if (_k > NTm1) _k = NTm1; \
        gl16(P[(h) * 2] + (size_t)_k * 64, &D[b][(h) * 8192 + ldst]); \
        gl16(P[(h) * 2 + 1] + (size_t)_k * 64, &D[b][(h) * 8192 + 4096 + ldst]); \
    } while (0)
#define LDA_(b, ih) do { \
        _Pragma("unroll") for (int iq = 0; iq < 4; iq++) \
        _Pragma("unroll") for (int kk = 0; kk < 2; kk++) \
            af[iq][kk] = *(const bf16x8*)&sA[b][((ih) * 128 + wr * 64 + iq * 16 + lm) * 64 + \
                                                (((q + kk * 4) ^ (lm & 7)) * 8)]; \
    } while (0)
#define LDB_(b, jh) do { \
        _Pragma("unroll") for (int jq = 0; jq < 2; jq++) \
        _Pragma("unroll") for (int kk = 0; kk < 2; kk++) \
            bfv[(jh) * 2 + jq][kk] = *(const bf16x8*)&sB[b][((jh) * 128 + wc * 32 + jq * 16 + lm) * 64 + \
                                                            (((q + kk * 4) ^ (lm & 7)) * 8)]; \
    } while (0)
#define MMA_(ih, jh) do { \
        __builtin_amdgcn_s_setprio(1); \
        _Pragma("unroll") for (int iq = 0; iq < 4; iq++) \
        _Pragma("unroll") for (int jq = 0; jq < 2; jq++) \
        _Pragma("unroll") for (int kk = 0; kk < 2; kk++) \
            acc[(ih) * 4 + iq][(jh) * 2 + jq] = __builtin_amdgcn_mfma_f32_16x16x32_bf16( \
                af[iq][kk], bfv[(jh) * 2 + jq][kk], acc[(ih) * 4 + iq][(jh) * 2 + jq], 0, 0, 0); \
        __builtin_amdgcn_s_setprio(0); \
    } while (0)
#define BAR asm volatile("s_barrier" ::: "memory")
#define VM6 asm volatile("s_waitcnt vmcnt(6)" ::: "memory")

    // prologue: tile0 fully + tile1 {A0, B1, A1}; vmcnt(6) -> tile0 landed.
    STG(pA, sA, 0, 0, 0);
    STG(pA, sA, 0, 1, 0);
    STG(pB, sB, 0, 0, 0);
    STG(pB, sB, 0, 1, 0);
    STG(pA, sA, 1, 0, 1);
    STG(pB, sB, 1, 1, 1);
    STG(pA, sA, 1, 1, 1);
    VM6;
    BAR;

    int S = NT >> 1;
    for (int s = 0; s < S; s++) {
        int t = s * 2;
        LDA_(0, 0); LDB_(0, 0);
        STG(pB, sB, 1, 0, t + 1);
        BAR; MMA_(0, 0); BAR;
        LDB_(0, 1);
        STG(pA, sA, 0, 0, t + 2);
        BAR; MMA_(0, 1); BAR;
        LDA_(0, 1);
        STG(pB, sB, 0, 1, t + 2);
        BAR; MMA_(1, 1); BAR;
        STG(pA, sA, 0, 1, t + 2);
        VM6;
        BAR; MMA_(1, 0); BAR;
        LDA_(1, 0); LDB_(1, 0);
        STG(pB, sB, 0, 0, t + 2);
        BAR; MMA_(0, 0); BAR;
        LDB_(1, 1);
        STG(pA, sA, 1, 0, t + 3);
        BAR; MMA_(0, 1); BAR;
        LDA_(1, 1);
        STG(pB, sB, 1, 1, t + 3);
        BAR; MMA_(1, 1); BAR;
        STG(pA, sA, 1, 1, t + 3);
        VM6;
        BAR; MMA_(1, 0); BAR;
    }
    asm volatile("s_waitcnt vmcnt(0)" ::: "memory");   // drain tail prefetches

    // epilogue: bias + optional QuickGELU; bf16 store, or fused f32 resid +=
#pragma unroll
    for (int ih = 0; ih < 2; ih++)
#pragma unroll
        for (int iq = 0; iq < 4; iq++) {
            int row_b = m0 + ih * 128 + wr * 64 + iq * 16 + q * 4;
#pragma unroll
            for (int jh = 0; jh < 2; jh++)
#pragma unroll
                for (int jq = 0; jq < 2; jq++) {
                    int col = n0 + jh * 128 + wc * 32 + jq * 16 + lm;
                    float bv = bias[col];
#pragma unroll
                    for (int r = 0; r < 4; r++) {
                        int row = row_b + r;
                        if (row < M) {
                            float v = acc[ih * 4 + iq][jh * 2 + jq][r] + bv;
                            if (gelu) v = v / (1.f + __expf(-1.702f * v));  // QuickGELU
                            if (Fout) {
                                size_t o = (size_t)row * N + col;
                                Fout[o] = Fout[o] + v;
                            } else {
                                Co[(size_t)row * N + col] = f2bf(v);
                            }
                        }
                    }
                }
        }
#undef STG
#undef LDA_
#undef LDB_
#undef MMA_
#undef BAR
#undef VM6
}

// ---------------------------------------------------------------------------
// Temporal attention: S=8.  4 (b,h) pairs per 256-thread block (one wave
// each); 1568%4==0 so all four share h.  Vectorized ushort4 staging.
// ---------------------------------------------------------------------------
__global__ __launch_bounds__(256) void attn_t(const u16* __restrict__ qkv,
                                              const float* __restrict__ rpb,
                                              u16* __restrict__ out) {
    int w = threadIdx.x >> 6, d = threadIdx.x & 63;
    int bh = blockIdx.x * 4 + w;           // 6272 blocks cover 25088 pairs
    int b = bh % 1568, h = bh / 1568;
    __shared__ float qs[4][8][68], ks[4][8][68], vs[4][8][68];
    __shared__ float ps[4][8][9];
#pragma unroll
    for (int tt = 0; tt < 2; tt++) {
        int t = tt * 4 + (d >> 4);
        int c4 = (d & 15) * 4;
        size_t row = (size_t)(t * 1568 + b) * 3072 + h * 64 + c4;
        ushort4 qv = *(const ushort4*)(qkv + row);
        ushort4 kv = *(const ushort4*)(qkv + row + 1024);
        ushort4 vv = *(const ushort4*)(qkv + row + 2048);
        qs[w][t][c4 + 0] = bf2f(qv.x) * 0.125f; qs[w][t][c4 + 1] = bf2f(qv.y) * 0.125f;
        qs[w][t][c4 + 2] = bf2f(qv.z) * 0.125f; qs[w][t][c4 + 3] = bf2f(qv.w) * 0.125f;
        ks[w][t][c4 + 0] = bf2f(kv.x); ks[w][t][c4 + 1] = bf2f(kv.y);
        ks[w][t][c4 + 2] = bf2f(kv.z); ks[w][t][c4 + 3] = bf2f(kv.w);
        vs[w][t][c4 + 0] = bf2f(vv.x); vs[w][t][c4 + 1] = bf2f(vv.y);
        vs[w][t][c4 + 2] = bf2f(vv.z); vs[w][t][c4 + 3] = bf2f(vv.w);
    }
    __syncthreads();
    int tq = d >> 3, tk = d & 7;
    float s = rpb[(tq - tk + 7) * 16 + h];
#pragma unroll
    for (int dd = 0; dd < 64; dd++) s += qs[w][tq][dd] * ks[w][tk][dd];
    float mx = s;
    mx = fmaxf(mx, __shfl_xor(mx, 1));
    mx = fmaxf(mx, __shfl_xor(mx, 2));
    mx = fmaxf(mx, __shfl_xor(mx, 4));
    float p = __expf(s - mx);
    float su = p;
    su += __shfl_xor(su, 1);
    su += __shfl_xor(su, 2);
    su += __shfl_xor(su, 4);
    ps[w][tq][tk] = p / su;
    __syncthreads();
#pragma unroll
    for (int t2 = 0; t2 < 8; t2++) {
        float o = 0.f;
#pragma unroll
        for (int k2 = 0; k2 < 8; k2++) o += ps[w][t2][k2] * vs[w][k2][d];
        out[(size_t)(t2 * 1568 + b) * 1024 + h * 64 + d] = f2bf(o);
    }
}

// ---------------------------------------------------------------------------
// Spatial attention, MFMA version.  S'=197 (13 q-tiles of 16, 13 k-tiles),
// one block(256)=4 waves per (u=t*8+n, h).  Barrier-free main loop
// (per-wave-private P; Kl/Vt read-only after staging barrier); two-phase PV
// over a halved P tile -> 80000 B LDS -> 2 blocks/CU.
// ---------------------------------------------------------------------------
#define KLS 72
#define PVS 232
#define PLW 136
__global__ __launch_bounds__(256) void attn_s(const u16* __restrict__ qkv,
                                              const float* __restrict__ rpb,
                                              u16* __restrict__ out) {
    __shared__ u16 Kl[208 * KLS];        // [key][feat], rows 197..207 zero
    __shared__ u16 Vt[64 * PVS];         // [feat][key], cols 197..231 zero
    __shared__ u16 Pl[4][16 * PLW];      // per-wave half-P tile
    __shared__ float rpb_l[736];
    int blk = blockIdx.x;
    int u = blk & 63, h = blk >> 6;
    int tid = threadIdx.x;
    int w = tid >> 6, lane = tid & 63;
    int lm = lane & 15, quad = lane >> 4;

    // ---- stage K, V^T ----
    for (int idx = tid; idx < 197 * 8; idx += 256) {
        int s = idx >> 3, c8 = idx & 7;
        const u16* gp = qkv + (size_t)(s * 64 + u) * 3072 + h * 64 + c8 * 8;
        uint4 kv = *(const uint4*)(gp + 1024);
        uint4 vv = *(const uint4*)(gp + 2048);
        *(uint4*)&Kl[s * KLS + c8 * 8] = kv;
        const u16* vp = (const u16*)&vv;
#pragma unroll
        for (int j = 0; j < 8; j++) Vt[(c8 * 8 + j) * PVS + s] = vp[j];
    }
    for (int i = tid; i < 11 * KLS; i += 256) Kl[197 * KLS + i] = 0;
    for (int i = tid; i < 64 * 35; i += 256) {
        int dd = i / 35, c = 197 + (i - dd * 35);
        Vt[dd * PVS + c] = 0;
    }
    for (int i = tid; i < 729; i += 256) rpb_l[i] = rpb[i * 16 + h];
    __syncthreads();

    for (int qt = w; qt < 13; qt += 4) {
        f32x4 sc[13];
        float rs[4];
        // Q A-frags straight from global: A[m=lm][k=quad*8+j]
        int qrow = qt * 16 + lm;
        int srq = qrow > 196 ? 196 : qrow;
        const u16* qp = qkv + (size_t)(srq * 64 + u) * 3072 + h * 64 + quad * 8;
        bf16x8 aq0 = *(const bf16x8*)qp;
        bf16x8 aq1 = *(const bf16x8*)(qp + 32);
        for (int kt = 0; kt < 13; kt++) {
            bf16x8 bk0 = *(const bf16x8*)&Kl[(kt * 16 + lm) * KLS + quad * 8];
            bf16x8 bk1 = *(const bf16x8*)&Kl[(kt * 16 + lm) * KLS + 32 + quad * 8];
            f32x4 s = __builtin_amdgcn_mfma_f32_16x16x32_bf16(aq0, bk0, (f32x4){0.f, 0.f, 0.f, 0.f}, 0, 0, 0);
            sc[kt] = __builtin_amdgcn_mfma_f32_16x16x32_bf16(aq1, bk1, s, 0, 0, 0);
        }
        int tk = lm;
#pragma unroll
        for (int r = 0; r < 4; r++) {
            int qr = qt * 16 + quad * 4 + r;
            int qcl = qr > 196 ? 196 : qr;
            int lq = qcl - 1;
            int qi = lq / 14, qj = lq - qi * 14;
            for (int kt = 0; kt < 13; kt++) {
                int tkk = kt * 16 + tk;
                float v;
                if (tkk >= 197) v = -1e30f;
                else {
                    v = sc[kt][r] * 0.125f;
                    if (qr >= 1 && tkk >= 1) {
                        int lk = tkk - 1;
                        int ki = lk / 14, kj = lk - ki * 14;
                        v += rpb_l[(qi - ki + 13) * 27 + (qj - kj + 13)];
                    }
                }
                sc[kt][r] = v;
            }
            float mx = -3e38f;
            for (int kt = 0; kt < 13; kt++) mx = fmaxf(mx, sc[kt][r]);
            mx = fmaxf(mx, __shfl_xor(mx, 1));
            mx = fmaxf(mx, __shfl_xor(mx, 2));
            mx = fmaxf(mx, __shfl_xor(mx, 4));
            mx = fmaxf(mx, __shfl_xor(mx, 8));
            float sm = 0.f;
            for (int kt = 0; kt < 13; kt++) {
                float p = __expf(sc[kt][r] - mx);
                sc[kt][r] = p;
                sm += p;
            }
            sm += __shfl_xor(sm, 1);
            sm += __shfl_xor(sm, 2);
            sm += __shfl_xor(sm, 4);
            sm += __shfl_xor(sm, 8);
            rs[r] = sm;
            // phase A: P cols 0..127 (kt 0..7)
            for (int kt = 0; kt < 8; kt++)
                Pl[w][(quad * 4 + r) * PLW + kt * 16 + tk] = f2bf(sc[kt][r]);
        }
        // phase A PV: kc 0..3 over P cols 0..127 (intra-wave dep; lgkmcnt)
        bf16x8 pa[7];
#pragma unroll
        for (int kc = 0; kc < 4; kc++)
            pa[kc] = *(const bf16x8*)&Pl[w][lm * PLW + kc * 32 + quad * 8];
        f32x4 o[4];
#pragma unroll
        for (int ct = 0; ct < 4; ct++) {
            o[ct] = (f32x4){0.f, 0.f, 0.f, 0.f};
#pragma unroll
            for (int kc = 0; kc < 4; kc++) {
                bf16x8 vb = *(const bf16x8*)&Vt[(ct * 16 + lm) * PVS + kc * 32 + quad * 8];
                o[ct] = __builtin_amdgcn_mfma_f32_16x16x32_bf16(pa[kc], vb, o[ct], 0, 0, 0);
            }
        }
        // phase B: overwrite P tile with cols 128..223 (kt 8..12 + zero pad)
#pragma unroll
        for (int r = 0; r < 4; r++)
            for (int kt = 8; kt < 13; kt++)
                Pl[w][(quad * 4 + r) * PLW + (kt - 8) * 16 + tk] = f2bf(sc[kt][r]);
        {   // zero local cols 80..95 (= global 208..223), overwritten by phase A
            int zr = lane >> 2, zc = 80 + (lane & 3) * 4;
            *(ushort4*)&Pl[w][zr * PLW + zc] = (ushort4){0, 0, 0, 0};
        }
#pragma unroll
        for (int kc = 4; kc < 7; kc++)
            pa[kc] = *(const bf16x8*)&Pl[w][lm * PLW + (kc - 4) * 32 + quad * 8];
#pragma unroll
        for (int ct = 0; ct < 4; ct++) {
#pragma unroll
            for (int kc = 4; kc < 7; kc++) {
                bf16x8 vb = *(const bf16x8*)&Vt[(ct * 16 + lm) * PVS + kc * 32 + quad * 8];
                o[ct] = __builtin_amdgcn_mfma_f32_16x16x32_bf16(pa[kc], vb, o[ct], 0, 0, 0);
            }
        }
        // store
#pragma unroll
        for (int ct = 0; ct < 4; ct++)
#pragma unroll
            for (int r = 0; r < 4; r++) {
                int qr = qt * 16 + quad * 4 + r;
                if (qr < 197)
                    out[(size_t)(qr * 64 + u) * 1024 + h * 64 + ct * 16 + lm] =
                        f2bf(o[ct][r] / rs[r]);
            }
    }
}

// ---------------------------------------------------------------------------
extern "C" void kernel_launch(void* const* d_in, const int* in_sizes, int n_in,
                              void* d_out, int out_size, void* d_ws, size_t ws_size,
                              hipStream_t stream) {
    const float* x      = (const float*)d_in[0];
    const float* pos_w  = (const float*)d_in[1];
    const float* pos_b  = (const float*)d_in[2];
    const float* ln_t_g = (const float*)d_in[3];
    const float* ln_t_b = (const float*)d_in[4];
    const float* rpb_t  = (const float*)d_in[5];
    const float* wqkv_t = (const float*)d_in[6];
    const float* bqkv_t = (const float*)d_in[7];
    const float* wo_t   = (const float*)d_in[8];
    const float* bo_t   = (const float*)d_in[9];
    const float* ln1_g  = (const float*)d_in[10];
    const float* ln1_b  = (const float*)d_in[11];
    const float* rpb_s  = (const float*)d_in[12];
    const float* wqkv_s = (const float*)d_in[13];
    const float* bqkv_s = (const float*)d_in[14];
    const float* wo_s   = (const float*)d_in[15];
    const float* bo_s   = (const float*)d_in[16];
    const float* ln2_g  = (const float*)d_in[17];
    const float* ln2_b  = (const float*)d_in[18];
    const float* fc_w   = (const float*)d_in[19];
    const float* fc_b   = (const float*)d_in[20];
    const float* proj_w = (const float*)d_in[21];
    const float* proj_b = (const float*)d_in[22];
    float* resid = (float*)d_out;

    // workspace arena (bf16 elements)
    u16* Wq_t  = (u16*)d_ws;
    u16* Wo_t  = Wq_t + 3145728;
    u16* Wq_s  = Wo_t + 1048576;
    u16* Wo_s  = Wq_s + 3145728;
    u16* Wfc   = Wo_s + 1048576;
    u16* Wpj   = Wfc  + 4194304;
    u16* Albuf = Wpj  + 4194304;          // 12608*1024
    u16* QKV   = Albuf + 12910592;        // 12608*3072
    u16* Obuf  = QKV   + 38731776;        // 12608*1024
    u16* Rbuf  = Obuf  + 12910592;        // 12608*1024
    u16* Hbuf  = QKV;                     // alias: 12552*4096 fits in QKV+Obuf
    float* wt  = (float*)QKV;             // alias: 27*1024 f32, used only by posembed

    // weight conversion + pos_w transpose (single merged launch)
    cvt_all<<<16492, 256, 0, stream>>>(
        (const float4*)wqkv_t, (ushort4*)Wq_t,
        (const float4*)wo_t,   (ushort4*)Wo_t,
        (const float4*)wqkv_s, (ushort4*)Wq_s,
        (const float4*)wo_s,   (ushort4*)Wo_s,
        (const float4*)fc_w,   (ushort4*)Wfc,
        (const float4*)proj_w, (ushort4*)Wpj,
        pos_w, wt);

    // positional embedding -> resid (= xpe)
    posembed<<<12552, 256, 0, stream>>>((const float4*)x, (const float4*)wt,
                                        (const float4*)pos_b, (float4*)resid);

    // temporal attention (result NOT added to resid; feeds spatial LN only)
    ln_kernel<<<12544, 256, 0, stream>>>(resid, nullptr, ln_t_g, ln_t_b, Albuf, 0);
    gemm_bf16<<<2352, 256, 0, stream>>>(Albuf, Wq_t, bqkv_t, QKV, 12544, 3072, 1024, 0, 24);
    attn_t<<<6272, 256, 0, stream>>>(QKV, rpb_t, Obuf);
    gemm_bf16<<<784, 256, 0, stream>>>(Obuf, Wo_t, bo_t, Rbuf, 12544, 1024, 1024, 0, 8);

    // spatial attention (LN1 fuses xt_full = xpe + rt gather)
    ln_kernel<<<12608, 256, 0, stream>>>(resid, Rbuf, ln1_g, ln1_b, Albuf, 1);
    gemm_bf16<<<2376, 256, 0, stream>>>(Albuf, Wq_s, bqkv_s, QKV, 12608, 3072, 1024, 0, 24);
    attn_s<<<1024, 256, 0, stream>>>(QKV, rpb_s, Obuf);
    // wo_s with fused spatial scatter-add AND fused cls frame-mean (atomics).
    gemm_wos<<<792, 256, 0, stream>>>(Obuf, Wo_s, bo_s, resid, 12608, 8);

    // MLP with QuickGELU; proj on the 8-phase 256^2 kernel (K=4096 long-K
    // regime) with fused f32 residual output.
    ln_kernel<<<12552, 256, 0, stream>>>(resid, nullptr, ln2_g, ln2_b, Albuf, 2);
    gemm_bf16<<<3168, 256, 0, stream>>>(Albuf, Wfc, fc_b, Hbuf, 12552, 4096, 1024, 1, 32);
    gemm256<<<200, 512, 0, stream>>>(Hbuf, Wpj, proj_b, nullptr, resid,
                                     12552, 1024, 4096, 0, 4);
}